// Round 4
// baseline (370.884 us; speedup 1.0000x reference)
//
#include <hip/hip_runtime.h>
#include <math.h>

#define Bx 8
#define IMG 128
#define DD 128
#define HEADS 4
#define LL 2
#define PCc 8
#define PFf 4
#define HCc 16
#define NCc 256
#define HFf 32
#define NFf 1024
#define NTOK 1280
#define HD 32

typedef __attribute__((ext_vector_type(8))) short short8;
typedef __attribute__((ext_vector_type(4))) float f32x4;

__device__ __forceinline__ short f2bf(float f) {
  unsigned u = __builtin_bit_cast(unsigned, f);
  u += 0x7FFF + ((u >> 16) & 1);   // RNE
  return (short)(u >> 16);
}

// ---------------- coarse patch embed: tokens[:, :256] = patch@Wpc + bpc + te[0]
__global__ __launch_bounds__(128) void k_coarse(const float* __restrict__ x,
    const float* __restrict__ Wpc, const float* __restrict__ bpc,
    const float* __restrict__ te, float* __restrict__ tokens) {
  int blk = blockIdx.x;            // b*NC + t
  int b = blk / NCc, t = blk % NCc;
  int hc = t / HCc, wc = t % HCc;
  int d = threadIdx.x;
  __shared__ float patch[PCc * PCc];
  if (d < PCc * PCc) {
    int pi = d / PCc, pj = d % PCc;
    patch[d] = x[(b * IMG + hc * PCc + pi) * IMG + wc * PCc + pj];
  }
  __syncthreads();
  float acc = bpc[d] + te[d];
  #pragma unroll 8
  for (int i = 0; i < PCc * PCc; ++i) acc += patch[i] * Wpc[i * DD + d];
  tokens[(size_t)(b * NTOK + t) * DD + d] = acc;
}

// ---------------- sobel -> avgpool4 -> mask -> stable-sort order + inverse
__global__ __launch_bounds__(1024) void k_edge_sort(const float* __restrict__ x,
    int* __restrict__ order, int* __restrict__ inv, float* __restrict__ msort) {
  int b = blockIdx.x;
  int t = threadIdx.x;             // 0..1023 -> fine cell (fy,fx)
  int fy = t >> 5, fx = t & 31;
  const float* img = x + (size_t)b * IMG * IMG;
  float s = 0.f;
  for (int dy = 0; dy < 4; ++dy) {
    for (int dx = 0; dx < 4; ++dx) {
      int py = fy * 4 + dy, px = fx * 4 + dx;
      float v[3][3];
      #pragma unroll
      for (int ky = 0; ky < 3; ++ky)
        #pragma unroll
        for (int kx = 0; kx < 3; ++kx) {
          int yy = py + ky - 1, xx = px + kx - 1;
          v[ky][kx] = (yy >= 0 && yy < IMG && xx >= 0 && xx < IMG)
                          ? img[yy * IMG + xx] : 0.f;
        }
      float gx = -v[0][0] + v[0][2] - 2.f * v[1][0] + 2.f * v[1][2] - v[2][0] + v[2][2];
      float gy = -v[0][0] - 2.f * v[0][1] - v[0][2] + v[2][0] + 2.f * v[2][1] + v[2][2];
      s += sqrtf(gx * gx + gy * gy);
    }
  }
  float e = s * (1.f / 16.f);
  __shared__ float red[1024];
  red[t] = e;
  __syncthreads();
  for (int off = 512; off > 0; off >>= 1) {
    if (t < off) red[t] += red[t + off];
    __syncthreads();
  }
  float mean = red[0] * (1.f / 1024.f);
  int m = (e > mean) ? 1 : 0;
  __shared__ int ps[1024];
  ps[t] = m;
  __syncthreads();
  for (int off = 1; off < 1024; off <<= 1) {
    int v2 = (t >= off) ? ps[t - off] : 0;
    __syncthreads();
    ps[t] += v2;
    __syncthreads();
  }
  int total = ps[1023];
  int incl = ps[t];
  int excl = incl - m;
  int pos = m ? excl : (total + t - excl);
  order[b * NFf + pos] = t;
  inv[b * NFf + t] = pos;
  msort[b * NFf + pos] = (float)m;
}

// ---------------- fine patch embed + direct scatter into tokens[:, 256:]
__global__ __launch_bounds__(128) void k_fine(const float* __restrict__ x,
    const float* __restrict__ Wpf, const float* __restrict__ bpf,
    const float* __restrict__ te, const int* __restrict__ inv,
    const float* __restrict__ msort, float* __restrict__ tokens) {
  int blk = blockIdx.x;            // b*NF + t
  int b = blk / NFf, t = blk % NFf;
  int hf = t / HFf, wf = t % HFf;
  int d = threadIdx.x;
  __shared__ float patch[PFf * PFf];
  if (d < PFf * PFf) {
    int pi = d / PFf, pj = d % PFf;
    patch[d] = x[(b * IMG + hf * PFf + pi) * IMG + wf * PFf + pj];
  }
  __syncthreads();
  float acc = bpf[d];
  #pragma unroll
  for (int i = 0; i < PFf * PFf; ++i) acc += patch[i] * Wpf[i * DD + d];
  int pos = inv[b * NFf + t];
  float mk = msort[b * NFf + pos];
  tokens[(size_t)(b * NTOK + NCc + pos) * DD + d] = acc * mk + te[DD + d];
}

// ---------------- weight prep: transpose + bf16 for all encoder GEMM weights
__global__ __launch_bounds__(256) void k_prep_w(const float* __restrict__ Wqkv,
    const float* __restrict__ Wo, const float* __restrict__ W1,
    const float* __restrict__ W2, short* __restrict__ WtQKV,
    short* __restrict__ WtO, short* __restrict__ Wt1, short* __restrict__ Wt2) {
  int idx = blockIdx.x * 256 + threadIdx.x;   // 0 .. 262143
  int l = idx / 131072, r = idx % 131072;
  const float* src; short* dst; int N, off;
  if (r < 49152)      { src = Wqkv + l * 49152; dst = WtQKV + l * 49152; N = 384; off = r; }
  else if (r < 65536) { src = Wo + l * 16384;  dst = WtO + l * 16384;  N = 128; off = r - 49152; }
  else if (r < 98304) { src = W1 + l * 32768;  dst = Wt1 + l * 32768;  N = 256; off = r - 65536; }
  else                { src = W2 + l * 32768;  dst = Wt2 + l * 32768;  N = 128; off = r - 98304; }
  int k = off / N, n = off % N;
  int K = (r >= 98304) ? 256 : 128;
  dst[(size_t)n * K + k] = f2bf(src[off]);
}

// ---------------- MFMA GEMM, optionally with fused LayerNorm on fp32 A.
// If lng!=null: Av is fp32 [M,128], LN(g,b) applied during staging (K must be 128).
// Else: Av is bf16 [M,K]. Wt bf16 [N][K]. Out: Cf fp32 += (residual) or Cb bf16 =.
// block 256 = 4 waves; tile 64 rows x 64 cols; K chunked at 128.
__global__ __launch_bounds__(256) void k_gemm_mfma(const void* __restrict__ Av,
    const short* __restrict__ Wt, const float* __restrict__ bias,
    const float* __restrict__ lng, const float* __restrict__ lnb,
    float* __restrict__ Cf, short* __restrict__ Cb, int K, int N, int do_gelu) {
  __shared__ short Alds[64 * 136];
  __shared__ short Blds[64 * 136];
  int row0 = blockIdx.x * 64, col0 = blockIdx.y * 64;
  int t = threadIdx.x;
  int lane = t & 63, w = t >> 6;
  int m = lane & 15, quad = lane >> 4;
  f32x4 zero = {0.f, 0.f, 0.f, 0.f};
  f32x4 acc[4] = {zero, zero, zero, zero};

  for (int kb = 0; kb < K; kb += 128) {
    __syncthreads();
    if (lng) {
      // fp32 A + fused LayerNorm (K == 128, single chunk)
      int r = t >> 2, seg = t & 3;           // 4 threads/row, 32 floats each
      const float* arow = (const float*)Av + (size_t)(row0 + r) * 128 + seg * 32;
      float vv[32];
      float s = 0.f, q = 0.f;
      #pragma unroll
      for (int j = 0; j < 8; ++j) {
        float4 u = ((const float4*)arow)[j];
        vv[j * 4 + 0] = u.x; vv[j * 4 + 1] = u.y;
        vv[j * 4 + 2] = u.z; vv[j * 4 + 3] = u.w;
        s += u.x + u.y + u.z + u.w;
        q += u.x * u.x + u.y * u.y + u.z * u.z + u.w * u.w;
      }
      s += __shfl_xor(s, 1); s += __shfl_xor(s, 2);
      q += __shfl_xor(q, 1); q += __shfl_xor(q, 2);
      float mean = s * (1.f / 128.f);
      float var = q * (1.f / 128.f) - mean * mean;
      float rstd = rsqrtf(var + 1e-5f);
      #pragma unroll
      for (int j8 = 0; j8 < 4; ++j8) {
        float4 g1 = ((const float4*)(lng + seg * 32))[j8 * 2];
        float4 g2 = ((const float4*)(lng + seg * 32))[j8 * 2 + 1];
        float4 b1 = ((const float4*)(lnb + seg * 32))[j8 * 2];
        float4 b2 = ((const float4*)(lnb + seg * 32))[j8 * 2 + 1];
        short8 o;
        o[0] = f2bf((vv[j8 * 8 + 0] - mean) * rstd * g1.x + b1.x);
        o[1] = f2bf((vv[j8 * 8 + 1] - mean) * rstd * g1.y + b1.y);
        o[2] = f2bf((vv[j8 * 8 + 2] - mean) * rstd * g1.z + b1.z);
        o[3] = f2bf((vv[j8 * 8 + 3] - mean) * rstd * g1.w + b1.w);
        o[4] = f2bf((vv[j8 * 8 + 4] - mean) * rstd * g2.x + b2.x);
        o[5] = f2bf((vv[j8 * 8 + 5] - mean) * rstd * g2.y + b2.y);
        o[6] = f2bf((vv[j8 * 8 + 6] - mean) * rstd * g2.z + b2.z);
        o[7] = f2bf((vv[j8 * 8 + 7] - mean) * rstd * g2.w + b2.w);
        *(short8*)&Alds[r * 136 + seg * 32 + j8 * 8] = o;
      }
      #pragma unroll
      for (int j = 0; j < 4; ++j) {
        int i = t + j * 256;
        int r2 = i >> 4, kk = (i & 15) * 8;
        *(short8*)&Blds[r2 * 136 + kk] =
            *(const short8*)&Wt[(size_t)(col0 + r2) * 128 + kk];
      }
    } else {
      const short* A = (const short*)Av;
      #pragma unroll
      for (int j = 0; j < 4; ++j) {
        int i = t + j * 256;
        int r2 = i >> 4, kk = (i & 15) * 8;
        *(short8*)&Alds[r2 * 136 + kk] =
            *(const short8*)&A[(size_t)(row0 + r2) * K + kb + kk];
        *(short8*)&Blds[r2 * 136 + kk] =
            *(const short8*)&Wt[(size_t)(col0 + r2) * K + kb + kk];
      }
    }
    __syncthreads();
    const short* Abase = Alds + (w * 16 + m) * 136 + quad * 8;
    const short* Bbase = Blds + m * 136 + quad * 8;
    #pragma unroll
    for (int ks = 0; ks < 128; ks += 32) {
      short8 af = *(const short8*)(Abase + ks);
      #pragma unroll
      for (int nt = 0; nt < 4; ++nt) {
        short8 bf = *(const short8*)(Bbase + nt * 16 * 136 + ks);
        acc[nt] = __builtin_amdgcn_mfma_f32_16x16x32_bf16(af, bf, acc[nt], 0, 0, 0);
      }
    }
  }
  // epilogue: C-layout row = quad*4+r, col = nt*16+m
  #pragma unroll
  for (int nt = 0; nt < 4; ++nt) {
    int col = col0 + nt * 16 + m;
    float bv = bias ? bias[col] : 0.f;
    #pragma unroll
    for (int r = 0; r < 4; ++r) {
      int row = row0 + w * 16 + quad * 4 + r;
      float v = acc[nt][r] + bv;
      if (do_gelu) v = 0.5f * v * (1.f + erff(v * 0.70710678118654752f));
      if (Cf) Cf[(size_t)row * N + col] += v;
      else    Cb[(size_t)row * N + col] = f2bf(v);
    }
  }
}

// ---------------- flash attention v2: direct-global K, double-buffered V,
// one barrier/stage, conflict-free LDS strides (74).
// grid = B*H*(NTOK/64); block = 256 (4 waves x 16 queries)
__global__ __launch_bounds__(256) void k_attn2(const short* __restrict__ qkv,
    short* __restrict__ obuf) {
  __shared__ short Vt[2][32 * 74];   // [d][key], stride 74: conflict-free scatter
  __shared__ short Pl[4][16 * 74];   // per-wave P [q][key]

  int qt = blockIdx.x % (NTOK / 64);
  int h  = (blockIdx.x / (NTOK / 64)) % HEADS;
  int b  = blockIdx.x / (NTOK / 64 * HEADS);
  int t = threadIdx.x;
  int lane = t & 63, w = t >> 6;
  int m = lane & 15, quad = lane >> 4;
  int q0 = qt * 64 + w * 16;

  const float scale = 0.17677669529663687f;  // 1/sqrt(32)
  short8 qf = *(const short8*)(qkv + ((size_t)(b * NTOK) + q0 + m) * 384 + h * HD + quad * 8);

  f32x4 zero = {0.f, 0.f, 0.f, 0.f};
  f32x4 Oacc[2] = {zero, zero};
  float mrow[4] = {-1e30f, -1e30f, -1e30f, -1e30f};
  float lrow[4] = {0.f, 0.f, 0.f, 0.f};

  int skey = t >> 2, sdseg = t & 3;  // V staging: key 0..63, 8 dims each
  const short* vstage = qkv + ((size_t)(b * NTOK) + skey) * 384 + 256 + h * HD + sdseg * 8;
  // direct-global K fragment base: key = s*64 + ct*16 + m, dims quad*8..+8
  const short* kbase = qkv + ((size_t)(b * NTOK) + m) * 384 + 128 + h * HD + quad * 8;

  { // prologue: stage V[0]
    short8 vf = *(const short8*)vstage;
    #pragma unroll
    for (int j = 0; j < 8; ++j) Vt[0][(sdseg * 8 + j) * 74 + skey] = vf[j];
  }
  __syncthreads();

  for (int s = 0; s < 20; ++s) {
    int cur = s & 1;
    short8 vf;
    bool pf = (s + 1 < 20);
    if (pf) vf = *(const short8*)(vstage + (size_t)(s + 1) * 64 * 384);

    // ---- S = Q K^T, K direct from global (C-layout: row=4*quad+reg, col=m)
    f32x4 sc[4];
    #pragma unroll
    for (int ct = 0; ct < 4; ++ct) {
      short8 kfrag = *(const short8*)(kbase + (size_t)(s * 64 + ct * 16) * 384);
      sc[ct] = __builtin_amdgcn_mfma_f32_16x16x32_bf16(qf, kfrag, zero, 0, 0, 0);
      sc[ct] *= scale;
    }
    // ---- online softmax (rows owned by 16-lane groups sharing `quad`)
    float mloc[4], psum[4];
    #pragma unroll
    for (int r = 0; r < 4; ++r) {
      float mx = fmaxf(fmaxf(sc[0][r], sc[1][r]), fmaxf(sc[2][r], sc[3][r]));
      #pragma unroll
      for (int o = 1; o < 16; o <<= 1) mx = fmaxf(mx, __shfl_xor(mx, o));
      float mnew = fmaxf(mrow[r], mx);
      float alpha = __expf(mrow[r] - mnew);
      mrow[r] = mnew;
      mloc[r] = alpha;
      float ssum = 0.f;
      #pragma unroll
      for (int ct = 0; ct < 4; ++ct) {
        float p = __expf(sc[ct][r] - mnew);
        sc[ct][r] = p;
        ssum += p;
      }
      psum[r] = ssum;
    }
    #pragma unroll
    for (int r = 0; r < 4; ++r) {
      float ssum = psum[r];
      #pragma unroll
      for (int o = 1; o < 16; o <<= 1) ssum += __shfl_xor(ssum, o);
      lrow[r] = lrow[r] * mloc[r] + ssum;
      Oacc[0][r] *= mloc[r];
      Oacc[1][r] *= mloc[r];
    }
    // ---- P (bf16) per-wave LDS, C-layout -> A-layout round trip
    #pragma unroll
    for (int ct = 0; ct < 4; ++ct)
      #pragma unroll
      for (int r = 0; r < 4; ++r)
        Pl[w][(quad * 4 + r) * 74 + ct * 16 + m] = f2bf(sc[ct][r]);
    // ---- O += P @ V  (Vt[cur] staged in a previous stage)
    #pragma unroll
    for (int ks = 0; ks < 2; ++ks) {
      short8 pfrag = *(const short8*)&Pl[w][m * 74 + ks * 32 + quad * 8];
      #pragma unroll
      for (int nt = 0; nt < 2; ++nt) {
        short8 vfrag = *(const short8*)&Vt[cur][(nt * 16 + m) * 74 + ks * 32 + quad * 8];
        Oacc[nt] = __builtin_amdgcn_mfma_f32_16x16x32_bf16(pfrag, vfrag, Oacc[nt], 0, 0, 0);
      }
    }
    // ---- stage V[s+1] into the other buffer
    if (pf) {
      #pragma unroll
      for (int j = 0; j < 8; ++j) Vt[cur ^ 1][(sdseg * 8 + j) * 74 + skey] = vf[j];
    }
    __syncthreads();
  }
  // ---- write O (C-layout: row q = 4*quad+reg, col d = nt*16 + m)
  #pragma unroll
  for (int r = 0; r < 4; ++r) {
    float rs = 1.f / lrow[r];
    int q = q0 + quad * 4 + r;
    #pragma unroll
    for (int nt = 0; nt < 2; ++nt)
      obuf[(size_t)(b * NTOK + q) * DD + h * HD + nt * 16 + m] = f2bf(Oacc[nt][r] * rs);
  }
}

// ---------------- coarse decoder head + 16->32 align-corners bilinear
__global__ __launch_bounds__(1024) void k_coarse_dec(const float* __restrict__ tokens,
    const float* __restrict__ dWc, const float* __restrict__ dbc,
    float* __restrict__ c_up) {
  int b = blockIdx.x;
  int t = threadIdx.x;
  __shared__ float c[NCc];
  if (t < NCc) {
    const float* row = tokens + (size_t)(b * NTOK + t) * DD;
    float a = 0.f;
    for (int d = 0; d < DD; ++d) a += row[d] * dWc[d];
    c[t] = a + dbc[0];
  }
  __syncthreads();
  int oy = t >> 5, ox = t & 31;
  float ys = oy * (15.f / 31.f);
  float xs = ox * (15.f / 31.f);
  int y0 = (int)floorf(ys); int y1 = min(y0 + 1, 15); float wy = ys - (float)y0;
  int x0 = (int)floorf(xs); int x1 = min(x0 + 1, 15); float wx = xs - (float)x0;
  float v = c[y0 * 16 + x0] * (1.f - wy) * (1.f - wx)
          + c[y0 * 16 + x1] * (1.f - wy) * wx
          + c[y1 * 16 + x0] * wy * (1.f - wx)
          + c[y1 * 16 + x1] * wy * wx;
  c_up[b * 1024 + t] = v;
}

// ---------------- fine decoder head, mask, scatter back to pixel order
__global__ __launch_bounds__(256) void k_fine_dec(const float* __restrict__ tokens,
    const float* __restrict__ dWf, const float* __restrict__ dbf,
    const float* __restrict__ msort, const int* __restrict__ order,
    float* __restrict__ f_map) {
  int idx = blockIdx.x * 256 + threadIdx.x;  // b*NF + j
  int b = idx >> 10, j = idx & 1023;
  const float* row = tokens + (size_t)(b * NTOK + NCc + j) * DD;
  float a = 0.f;
  for (int d = 0; d < DD; ++d) a += row[d] * dWf[d];
  a = (a + dbf[0]) * msort[b * NFf + j];
  f_map[b * NFf + order[b * NFf + j]] = a;  // 32->32 AC-bilinear is identity
}

// ---------------- fused 2-ch conv3x3 + relu + conv3x3 -> out
__global__ __launch_bounds__(1024) void k_fuse_conv(const float* __restrict__ c_up,
    const float* __restrict__ f_map, const float* __restrict__ fW1,
    const float* __restrict__ fb1, const float* __restrict__ fW2,
    const float* __restrict__ fb2, float* __restrict__ outp) {
  int b = blockIdx.x;
  int t = threadIdx.x;
  int y = t >> 5, x = t & 31;
  __shared__ float fin[2][1024];
  __shared__ float hb[2][1024];
  fin[0][t] = c_up[b * 1024 + t];
  fin[1][t] = f_map[b * 1024 + t];
  __syncthreads();
  for (int oc = 0; oc < 2; ++oc) {
    float a = fb1[oc];
    #pragma unroll
    for (int ic = 0; ic < 2; ++ic)
      #pragma unroll
      for (int ky = 0; ky < 3; ++ky)
        #pragma unroll
        for (int kx = 0; kx < 3; ++kx) {
          int yy = y + ky - 1, xx = x + kx - 1;
          float v = (yy >= 0 && yy < 32 && xx >= 0 && xx < 32)
                        ? fin[ic][yy * 32 + xx] : 0.f;
          a += v * fW1[((oc * 2 + ic) * 3 + ky) * 3 + kx];
        }
    hb[oc][t] = fmaxf(a, 0.f);
  }
  __syncthreads();
  float a = fb2[0];
  #pragma unroll
  for (int ic = 0; ic < 2; ++ic)
    #pragma unroll
    for (int ky = 0; ky < 3; ++ky)
      #pragma unroll
      for (int kx = 0; kx < 3; ++kx) {
        int yy = y + ky - 1, xx = x + kx - 1;
        float v = (yy >= 0 && yy < 32 && xx >= 0 && xx < 32)
                      ? hb[ic][yy * 32 + xx] : 0.f;
        a += v * fW2[(ic * 3 + ky) * 3 + kx];
      }
  outp[b * 1024 + t] = a;
}

extern "C" void kernel_launch(void* const* d_in, const int* in_sizes, int n_in,
                              void* d_out, int out_size, void* d_ws, size_t ws_size,
                              hipStream_t stream) {
  const float* x    = (const float*)d_in[0];
  const float* Wpc  = (const float*)d_in[1];
  const float* bpc  = (const float*)d_in[2];
  const float* Wpf  = (const float*)d_in[3];
  const float* bpf  = (const float*)d_in[4];
  const float* te   = (const float*)d_in[5];
  const float* ln1g = (const float*)d_in[6];
  const float* ln1b = (const float*)d_in[7];
  const float* Wqkv = (const float*)d_in[8];
  const float* Wo   = (const float*)d_in[9];
  const float* bo   = (const float*)d_in[10];
  const float* ln2g = (const float*)d_in[11];
  const float* ln2b = (const float*)d_in[12];
  const float* W1   = (const float*)d_in[13];
  const float* b1   = (const float*)d_in[14];
  const float* W2   = (const float*)d_in[15];
  const float* b2   = (const float*)d_in[16];
  const float* dWc  = (const float*)d_in[17];
  const float* dbc  = (const float*)d_in[18];
  const float* dWf  = (const float*)d_in[19];
  const float* dbf  = (const float*)d_in[20];
  const float* fW1  = (const float*)d_in[21];
  const float* fb1  = (const float*)d_in[22];
  const float* fW2  = (const float*)d_in[23];
  const float* fb2  = (const float*)d_in[24];

  char* ws = (char*)d_ws;
  float* tokens = (float*)ws;                 ws += 1310720 * 4;   // fp32 [B*N,128]
  short* qkvb   = (short*)ws;                 ws += 3932160 * 2;   // bf16 [B*N,384]
  short* obuf   = (short*)ws;                 ws += 1310720 * 2;   // bf16
  short* hbuf   = (short*)ws;                 ws += 2621440 * 2;   // bf16 [B*N,256]
  short* WtQKV  = (short*)ws;                 ws += 98304 * 2;     // [L][384][128]
  short* WtO    = (short*)ws;                 ws += 32768 * 2;     // [L][128][128]
  short* Wt1    = (short*)ws;                 ws += 65536 * 2;     // [L][256][128]
  short* Wt2    = (short*)ws;                 ws += 65536 * 2;     // [L][128][256]
  float* msort  = (float*)ws;                 ws += 8192 * 4;
  float* c_up   = (float*)ws;                 ws += 8192 * 4;
  float* f_map  = (float*)ws;                 ws += 8192 * 4;
  int*   order  = (int*)ws;                   ws += 8192 * 4;
  int*   inv    = (int*)ws;                   ws += 8192 * 4;

  const int M = Bx * NTOK;                    // 10240

  k_prep_w<<<1024, 256, 0, stream>>>(Wqkv, Wo, W1, W2, WtQKV, WtO, Wt1, Wt2);
  k_coarse<<<Bx * NCc, 128, 0, stream>>>(x, Wpc, bpc, te, tokens);
  k_edge_sort<<<Bx, 1024, 0, stream>>>(x, order, inv, msort);
  k_fine<<<Bx * NFf, 128, 0, stream>>>(x, Wpf, bpf, te, inv, msort, tokens);

  for (int l = 0; l < LL; ++l) {
    k_gemm_mfma<<<dim3(M / 64, 384 / 64), 256, 0, stream>>>(
        tokens, WtQKV + (size_t)l * 49152, nullptr,
        ln1g + l * DD, ln1b + l * DD, nullptr, qkvb, 128, 384, 0);
    k_attn2<<<Bx * HEADS * (NTOK / 64), 256, 0, stream>>>(qkvb, obuf);
    k_gemm_mfma<<<dim3(M / 64, 128 / 64), 256, 0, stream>>>(
        obuf, WtO + (size_t)l * 16384, bo + l * DD,
        nullptr, nullptr, tokens, nullptr, 128, 128, 0);
    k_gemm_mfma<<<dim3(M / 64, 256 / 64), 256, 0, stream>>>(
        tokens, Wt1 + (size_t)l * 32768, b1 + l * 256,
        ln2g + l * DD, ln2b + l * DD, nullptr, hbuf, 128, 256, 1);
    k_gemm_mfma<<<dim3(M / 64, 128 / 64), 256, 0, stream>>>(
        hbuf, Wt2 + (size_t)l * 32768, b2 + l * DD,
        nullptr, nullptr, tokens, nullptr, 256, 128, 0);
  }

  k_coarse_dec<<<Bx, 1024, 0, stream>>>(tokens, dWc, dbc, c_up);
  k_fine_dec<<<Bx * NFf / 256, 256, 0, stream>>>(tokens, dWf, dbf, msort, order, f_map);
  k_fuse_conv<<<Bx, 1024, 0, stream>>>(c_up, f_map, fW1, fb1, fW2, fb2, (float*)d_out);
}

// Round 5
// 317.239 us; speedup vs baseline: 1.1691x; 1.1691x over previous
//
#include <hip/hip_runtime.h>
#include <math.h>

#define Bx 8
#define IMG 128
#define DD 128
#define HEADS 4
#define LL 2
#define PCc 8
#define PFf 4
#define HCc 16
#define NCc 256
#define HFf 32
#define NFf 1024
#define NTOK 1280
#define HD 32
#define SPLIT 4          // key-split factor for flash-decode attention
#define NQT 20           // NTOK/64 query tiles

typedef __attribute__((ext_vector_type(8))) short short8;
typedef __attribute__((ext_vector_type(4))) float f32x4;

__device__ __forceinline__ short f2bf(float f) {
  unsigned u = __builtin_bit_cast(unsigned, f);
  u += 0x7FFF + ((u >> 16) & 1);   // RNE
  return (short)(u >> 16);
}
__device__ __forceinline__ float bf2f(short s) {
  unsigned u = ((unsigned)(unsigned short)s) << 16;
  return __builtin_bit_cast(float, u);
}

// ---------------- coarse patch embed: tokens[:, :256] = patch@Wpc + bpc + te[0]
__global__ __launch_bounds__(128) void k_coarse(const float* __restrict__ x,
    const float* __restrict__ Wpc, const float* __restrict__ bpc,
    const float* __restrict__ te, float* __restrict__ tokens) {
  int blk = blockIdx.x;            // b*NC + t
  int b = blk / NCc, t = blk % NCc;
  int hc = t / HCc, wc = t % HCc;
  int d = threadIdx.x;
  __shared__ float patch[PCc * PCc];
  if (d < PCc * PCc) {
    int pi = d / PCc, pj = d % PCc;
    patch[d] = x[(b * IMG + hc * PCc + pi) * IMG + wc * PCc + pj];
  }
  __syncthreads();
  float acc = bpc[d] + te[d];
  #pragma unroll 8
  for (int i = 0; i < PCc * PCc; ++i) acc += patch[i] * Wpc[i * DD + d];
  tokens[(size_t)(b * NTOK + t) * DD + d] = acc;
}

// ---------------- sobel -> avgpool4 -> mask -> stable-sort order via ballot scan
__global__ __launch_bounds__(1024) void k_edge_sort(const float* __restrict__ x,
    int* __restrict__ order, int* __restrict__ inv, float* __restrict__ msort) {
  int b = blockIdx.x;
  int t = threadIdx.x;             // 0..1023 -> fine cell (fy,fx)
  int lane = t & 63, wave = t >> 6;
  int fy = t >> 5, fx = t & 31;
  const float* img = x + (size_t)b * IMG * IMG;
  float s = 0.f;
  for (int dy = 0; dy < 4; ++dy) {
    for (int dx = 0; dx < 4; ++dx) {
      int py = fy * 4 + dy, px = fx * 4 + dx;
      float v[3][3];
      #pragma unroll
      for (int ky = 0; ky < 3; ++ky)
        #pragma unroll
        for (int kx = 0; kx < 3; ++kx) {
          int yy = py + ky - 1, xx = px + kx - 1;
          v[ky][kx] = (yy >= 0 && yy < IMG && xx >= 0 && xx < IMG)
                          ? img[yy * IMG + xx] : 0.f;
        }
      float gx = -v[0][0] + v[0][2] - 2.f * v[1][0] + 2.f * v[1][2] - v[2][0] + v[2][2];
      float gy = -v[0][0] - 2.f * v[0][1] - v[0][2] + v[2][0] + 2.f * v[2][1] + v[2][2];
      s += sqrtf(gx * gx + gy * gy);
    }
  }
  float e = s * (1.f / 16.f);
  // block mean via wave shuffle + 16-entry LDS
  __shared__ float wsum[16];
  __shared__ int wcnt[16];
  float r = e;
  #pragma unroll
  for (int o = 32; o > 0; o >>= 1) r += __shfl_xor(r, o, 64);
  if (lane == 0) wsum[wave] = r;
  __syncthreads();
  float tot = 0.f;
  #pragma unroll
  for (int i = 0; i < 16; ++i) tot += wsum[i];
  float mean = tot * (1.f / 1024.f);
  int m = (e > mean) ? 1 : 0;
  // stable partition position via ballot + popcount
  unsigned long long bal = __ballot(m);
  if (lane == 0) wcnt[wave] = __popcll(bal);
  __syncthreads();
  int wbase = 0, total = 0;
  #pragma unroll
  for (int i = 0; i < 16; ++i) {
    int c = wcnt[i];
    if (i < wave) wbase += c;
    total += c;
  }
  unsigned long long below = (lane == 63) ? ~0ULL : ((1ULL << (lane + 1)) - 1);
  int incl = __popcll(bal & below);
  int eb = wbase + incl - m;       // edges strictly before t
  int pos = m ? eb : (total + t - eb);
  order[b * NFf + pos] = t;
  inv[b * NFf + t] = pos;
  msort[b * NFf + pos] = (float)m;
}

// ---------------- fine patch embed + direct scatter into tokens[:, 256:]
__global__ __launch_bounds__(128) void k_fine(const float* __restrict__ x,
    const float* __restrict__ Wpf, const float* __restrict__ bpf,
    const float* __restrict__ te, const int* __restrict__ inv,
    const float* __restrict__ msort, float* __restrict__ tokens) {
  int blk = blockIdx.x;            // b*NF + t
  int b = blk / NFf, t = blk % NFf;
  int hf = t / HFf, wf = t % HFf;
  int d = threadIdx.x;
  __shared__ float patch[PFf * PFf];
  if (d < PFf * PFf) {
    int pi = d / PFf, pj = d % PFf;
    patch[d] = x[(b * IMG + hf * PFf + pi) * IMG + wf * PFf + pj];
  }
  __syncthreads();
  float acc = bpf[d];
  #pragma unroll
  for (int i = 0; i < PFf * PFf; ++i) acc += patch[i] * Wpf[i * DD + d];
  int pos = inv[b * NFf + t];
  float mk = msort[b * NFf + pos];
  tokens[(size_t)(b * NTOK + NCc + pos) * DD + d] = acc * mk + te[DD + d];
}

// ---------------- weight prep: transpose + bf16 for all encoder GEMM weights
__global__ __launch_bounds__(256) void k_prep_w(const float* __restrict__ Wqkv,
    const float* __restrict__ Wo, const float* __restrict__ W1,
    const float* __restrict__ W2, short* __restrict__ WtQKV,
    short* __restrict__ WtO, short* __restrict__ Wt1, short* __restrict__ Wt2) {
  int idx = blockIdx.x * 256 + threadIdx.x;   // 0 .. 262143
  int l = idx / 131072, r = idx % 131072;
  const float* src; short* dst; int N, off;
  if (r < 49152)      { src = Wqkv + l * 49152; dst = WtQKV + l * 49152; N = 384; off = r; }
  else if (r < 65536) { src = Wo + l * 16384;  dst = WtO + l * 16384;  N = 128; off = r - 49152; }
  else if (r < 98304) { src = W1 + l * 32768;  dst = Wt1 + l * 32768;  N = 256; off = r - 65536; }
  else                { src = W2 + l * 32768;  dst = Wt2 + l * 32768;  N = 128; off = r - 98304; }
  int k = off / N, n = off % N;
  int K = (r >= 98304) ? 256 : 128;
  dst[(size_t)n * K + k] = f2bf(src[off]);
}

// ---------------- LayerNorm over D=128, one wave per row, out bf16
__global__ __launch_bounds__(256) void k_ln_bf16(const float* __restrict__ inp,
    const float* __restrict__ g, const float* __restrict__ bb,
    short* __restrict__ outp) {
  int row = blockIdx.x * 4 + (threadIdx.x >> 6);
  int lane = threadIdx.x & 63;
  float2 v = ((const float2*)(inp + (size_t)row * DD))[lane];
  float s = v.x + v.y;
  #pragma unroll
  for (int o = 32; o > 0; o >>= 1) s += __shfl_xor(s, o, 64);
  float mean = s * (1.f / 128.f);
  float cx = v.x - mean, cy = v.y - mean;
  float q = cx * cx + cy * cy;
  #pragma unroll
  for (int o = 32; o > 0; o >>= 1) q += __shfl_xor(q, o, 64);
  float rstd = rsqrtf(q * (1.f / 128.f) + 1e-5f);
  float2 gg = ((const float2*)g)[lane];
  float2 bv = ((const float2*)bb)[lane];
  int p = (int)(unsigned short)f2bf(cx * rstd * gg.x + bv.x)
        | ((int)(unsigned short)f2bf(cy * rstd * gg.y + bv.y) << 16);
  ((int*)(outp + (size_t)row * DD))[lane] = p;
}

// ---------------- MFMA GEMM: C[M,N] = act(A_bf16[M,K] @ W + bias)
// Wt bf16 [N][K]. Out: Cf fp32 += (residual) or Cb bf16 =.
__global__ __launch_bounds__(256) void k_gemm_mfma(const short* __restrict__ A,
    const short* __restrict__ Wt, const float* __restrict__ bias,
    float* __restrict__ Cf, short* __restrict__ Cb, int K, int N, int do_gelu) {
  __shared__ short Alds[64 * 136];
  __shared__ short Blds[64 * 136];
  int row0 = blockIdx.x * 64, col0 = blockIdx.y * 64;
  int t = threadIdx.x;
  int lane = t & 63, w = t >> 6;
  int m = lane & 15, quad = lane >> 4;
  f32x4 zero = {0.f, 0.f, 0.f, 0.f};
  f32x4 acc[4] = {zero, zero, zero, zero};

  for (int kb = 0; kb < K; kb += 128) {
    __syncthreads();
    #pragma unroll
    for (int j = 0; j < 4; ++j) {
      int i = t + j * 256;
      int r2 = i >> 4, kk = (i & 15) * 8;
      *(short8*)&Alds[r2 * 136 + kk] =
          *(const short8*)&A[(size_t)(row0 + r2) * K + kb + kk];
      *(short8*)&Blds[r2 * 136 + kk] =
          *(const short8*)&Wt[(size_t)(col0 + r2) * K + kb + kk];
    }
    __syncthreads();
    const short* Abase = Alds + (w * 16 + m) * 136 + quad * 8;
    const short* Bbase = Blds + m * 136 + quad * 8;
    #pragma unroll
    for (int ks = 0; ks < 128; ks += 32) {
      short8 af = *(const short8*)(Abase + ks);
      #pragma unroll
      for (int nt = 0; nt < 4; ++nt) {
        short8 bf = *(const short8*)(Bbase + nt * 16 * 136 + ks);
        acc[nt] = __builtin_amdgcn_mfma_f32_16x16x32_bf16(af, bf, acc[nt], 0, 0, 0);
      }
    }
  }
  #pragma unroll
  for (int nt = 0; nt < 4; ++nt) {
    int col = col0 + nt * 16 + m;
    float bv = bias ? bias[col] : 0.f;
    #pragma unroll
    for (int r = 0; r < 4; ++r) {
      int row = row0 + w * 16 + quad * 4 + r;
      float v = acc[nt][r] + bv;
      if (do_gelu) v = 0.5f * v * (1.f + erff(v * 0.70710678118654752f));
      if (Cf) Cf[(size_t)row * N + col] += v;
      else    Cb[(size_t)row * N + col] = f2bf(v);
    }
  }
}

// ---------------- flash attention, split-K (flash-decode style)
// grid = B*H*NQT*SPLIT; block = 256 (4 waves x 16 queries)
// each block covers 320 keys (5 stages of 64); partials merged by k_attn_combine
__global__ __launch_bounds__(256) void k_attn3(const short* __restrict__ qkv,
    short* __restrict__ Opart, float* __restrict__ Mpart, float* __restrict__ Lpart) {
  __shared__ short Ks[64 * 32];      // [key][d]
  __shared__ short Vt[32 * 74];      // [d][key], stride 74
  __shared__ short Pl[4][16 * 74];   // per-wave P [q][key]

  int sk = blockIdx.x % SPLIT;
  int qt = (blockIdx.x / SPLIT) % NQT;
  int h  = (blockIdx.x / (SPLIT * NQT)) % HEADS;
  int b  = blockIdx.x / (SPLIT * NQT * HEADS);
  int t = threadIdx.x;
  int lane = t & 63, w = t >> 6;
  int m = lane & 15, quad = lane >> 4;
  int q0 = qt * 64 + w * 16;

  const float scale = 0.17677669529663687f;  // 1/sqrt(32)
  short8 qf = *(const short8*)(qkv + ((size_t)(b * NTOK) + q0 + m) * 384 + h * HD + quad * 8);

  f32x4 zero = {0.f, 0.f, 0.f, 0.f};
  f32x4 Oacc[2] = {zero, zero};
  float mrow[4] = {-1e30f, -1e30f, -1e30f, -1e30f};
  float lrow[4] = {0.f, 0.f, 0.f, 0.f};

  int skey = t >> 2, sdseg = t & 3;  // staging: key 0..63, 8 dims each
  const short* kstage = qkv + ((size_t)(b * NTOK) + skey) * 384 + 128 + h * HD + sdseg * 8;

  for (int s = sk * 5; s < sk * 5 + 5; ++s) {
    __syncthreads();
    {
      short8 kf = *(const short8*)(kstage + (size_t)s * 64 * 384);
      *(short8*)&Ks[skey * 32 + sdseg * 8] = kf;
      short8 vf = *(const short8*)(kstage + 128 + (size_t)s * 64 * 384);
      #pragma unroll
      for (int j = 0; j < 8; ++j) Vt[(sdseg * 8 + j) * 74 + skey] = vf[j];
    }
    __syncthreads();

    f32x4 sc[4];
    #pragma unroll
    for (int ct = 0; ct < 4; ++ct) {
      short8 kfrag = *(const short8*)&Ks[(ct * 16 + m) * 32 + quad * 8];
      sc[ct] = __builtin_amdgcn_mfma_f32_16x16x32_bf16(qf, kfrag, zero, 0, 0, 0);
      sc[ct] *= scale;
    }
    float mloc[4], psum[4];
    #pragma unroll
    for (int r = 0; r < 4; ++r) {
      float mx = fmaxf(fmaxf(sc[0][r], sc[1][r]), fmaxf(sc[2][r], sc[3][r]));
      #pragma unroll
      for (int o = 1; o < 16; o <<= 1) mx = fmaxf(mx, __shfl_xor(mx, o));
      float mnew = fmaxf(mrow[r], mx);
      float alpha = __expf(mrow[r] - mnew);
      mrow[r] = mnew;
      mloc[r] = alpha;
      float ssum = 0.f;
      #pragma unroll
      for (int ct = 0; ct < 4; ++ct) {
        float p = __expf(sc[ct][r] - mnew);
        sc[ct][r] = p;
        ssum += p;
      }
      psum[r] = ssum;
    }
    #pragma unroll
    for (int r = 0; r < 4; ++r) {
      float ssum = psum[r];
      #pragma unroll
      for (int o = 1; o < 16; o <<= 1) ssum += __shfl_xor(ssum, o);
      lrow[r] = lrow[r] * mloc[r] + ssum;
      Oacc[0][r] *= mloc[r];
      Oacc[1][r] *= mloc[r];
    }
    #pragma unroll
    for (int ct = 0; ct < 4; ++ct)
      #pragma unroll
      for (int r = 0; r < 4; ++r)
        Pl[w][(quad * 4 + r) * 74 + ct * 16 + m] = f2bf(sc[ct][r]);
    #pragma unroll
    for (int ks = 0; ks < 2; ++ks) {
      short8 pfrag = *(const short8*)&Pl[w][m * 74 + ks * 32 + quad * 8];
      #pragma unroll
      for (int nt = 0; nt < 2; ++nt) {
        short8 vfrag = *(const short8*)&Vt[(nt * 16 + m) * 74 + ks * 32 + quad * 8];
        Oacc[nt] = __builtin_amdgcn_mfma_f32_16x16x32_bf16(pfrag, vfrag, Oacc[nt], 0, 0, 0);
      }
    }
  }
  // write partials: unnormalized O (bf16), m,l per q-row
  #pragma unroll
  for (int r = 0; r < 4; ++r) {
    int qloc = w * 16 + quad * 4 + r;
    #pragma unroll
    for (int nt = 0; nt < 2; ++nt)
      Opart[(size_t)blockIdx.x * 2048 + qloc * 32 + nt * 16 + m] = f2bf(Oacc[nt][r]);
    if (m == 0) {
      Mpart[(size_t)blockIdx.x * 64 + qloc] = mrow[r];
      Lpart[(size_t)blockIdx.x * 64 + qloc] = lrow[r];
    }
  }
}

// ---------------- combine split-K partials -> obuf bf16
// grid = B*H*NQT; block 256: thread = q(0..63)*4 + seg(0..3, 8 dims)
__global__ __launch_bounds__(256) void k_attn_combine(const short* __restrict__ Opart,
    const float* __restrict__ Mpart, const float* __restrict__ Lpart,
    short* __restrict__ obuf) {
  int blk = blockIdx.x;
  int qt = blk % NQT, h = (blk / NQT) % HEADS, b = blk / (NQT * HEADS);
  int t = threadIdx.x;
  int q = t >> 2, seg = t & 3;
  size_t pbase = (size_t)blk * SPLIT;
  float mv[SPLIT], lv[SPLIT];
  float M = -1e30f;
  #pragma unroll
  for (int sk = 0; sk < SPLIT; ++sk) {
    mv[sk] = Mpart[(pbase + sk) * 64 + q];
    lv[sk] = Lpart[(pbase + sk) * 64 + q];
    M = fmaxf(M, mv[sk]);
  }
  float L = 0.f, wgt[SPLIT];
  #pragma unroll
  for (int sk = 0; sk < SPLIT; ++sk) {
    wgt[sk] = __expf(mv[sk] - M);
    L += lv[sk] * wgt[sk];
  }
  float o[8] = {0, 0, 0, 0, 0, 0, 0, 0};
  #pragma unroll
  for (int sk = 0; sk < SPLIT; ++sk) {
    short8 po = *(const short8*)&Opart[(pbase + sk) * 2048 + q * 32 + seg * 8];
    #pragma unroll
    for (int j = 0; j < 8; ++j) o[j] += bf2f(po[j]) * wgt[sk];
  }
  float rs = 1.f / L;
  short8 ov;
  #pragma unroll
  for (int j = 0; j < 8; ++j) ov[j] = f2bf(o[j] * rs);
  *(short8*)&obuf[(size_t)(b * NTOK + qt * 64 + q) * DD + h * HD + seg * 8] = ov;
}

// ---------------- coarse decoder head + 16->32 align-corners bilinear
__global__ __launch_bounds__(1024) void k_coarse_dec(const float* __restrict__ tokens,
    const float* __restrict__ dWc, const float* __restrict__ dbc,
    float* __restrict__ c_up) {
  int b = blockIdx.x;
  int t = threadIdx.x;
  __shared__ float c[NCc];
  if (t < NCc) {
    const float* row = tokens + (size_t)(b * NTOK + t) * DD;
    float a = 0.f;
    for (int d = 0; d < DD; ++d) a += row[d] * dWc[d];
    c[t] = a + dbc[0];
  }
  __syncthreads();
  int oy = t >> 5, ox = t & 31;
  float ys = oy * (15.f / 31.f);
  float xs = ox * (15.f / 31.f);
  int y0 = (int)floorf(ys); int y1 = min(y0 + 1, 15); float wy = ys - (float)y0;
  int x0 = (int)floorf(xs); int x1 = min(x0 + 1, 15); float wx = xs - (float)x0;
  float v = c[y0 * 16 + x0] * (1.f - wy) * (1.f - wx)
          + c[y0 * 16 + x1] * (1.f - wy) * wx
          + c[y1 * 16 + x0] * wy * (1.f - wx)
          + c[y1 * 16 + x1] * wy * wx;
  c_up[b * 1024 + t] = v;
}

// ---------------- fine decoder head, mask, scatter back to pixel order
__global__ __launch_bounds__(256) void k_fine_dec(const float* __restrict__ tokens,
    const float* __restrict__ dWf, const float* __restrict__ dbf,
    const float* __restrict__ msort, const int* __restrict__ order,
    float* __restrict__ f_map) {
  int idx = blockIdx.x * 256 + threadIdx.x;  // b*NF + j
  int b = idx >> 10, j = idx & 1023;
  const float* row = tokens + (size_t)(b * NTOK + NCc + j) * DD;
  float a = 0.f;
  for (int d = 0; d < DD; ++d) a += row[d] * dWf[d];
  a = (a + dbf[0]) * msort[b * NFf + j];
  f_map[b * NFf + order[b * NFf + j]] = a;  // 32->32 AC-bilinear is identity
}

// ---------------- fused 2-ch conv3x3 + relu + conv3x3 -> out
__global__ __launch_bounds__(1024) void k_fuse_conv(const float* __restrict__ c_up,
    const float* __restrict__ f_map, const float* __restrict__ fW1,
    const float* __restrict__ fb1, const float* __restrict__ fW2,
    const float* __restrict__ fb2, float* __restrict__ outp) {
  int b = blockIdx.x;
  int t = threadIdx.x;
  int y = t >> 5, x = t & 31;
  __shared__ float fin[2][1024];
  __shared__ float hb[2][1024];
  fin[0][t] = c_up[b * 1024 + t];
  fin[1][t] = f_map[b * 1024 + t];
  __syncthreads();
  for (int oc = 0; oc < 2; ++oc) {
    float a = fb1[oc];
    #pragma unroll
    for (int ic = 0; ic < 2; ++ic)
      #pragma unroll
      for (int ky = 0; ky < 3; ++ky)
        #pragma unroll
        for (int kx = 0; kx < 3; ++kx) {
          int yy = y + ky - 1, xx = x + kx - 1;
          float v = (yy >= 0 && yy < 32 && xx >= 0 && xx < 32)
                        ? fin[ic][yy * 32 + xx] : 0.f;
          a += v * fW1[((oc * 2 + ic) * 3 + ky) * 3 + kx];
        }
    hb[oc][t] = fmaxf(a, 0.f);
  }
  __syncthreads();
  float a = fb2[0];
  #pragma unroll
  for (int ic = 0; ic < 2; ++ic)
    #pragma unroll
    for (int ky = 0; ky < 3; ++ky)
      #pragma unroll
      for (int kx = 0; kx < 3; ++kx) {
        int yy = y + ky - 1, xx = x + kx - 1;
        float v = (yy >= 0 && yy < 32 && xx >= 0 && xx < 32)
                      ? hb[ic][yy * 32 + xx] : 0.f;
        a += v * fW2[(ic * 3 + ky) * 3 + kx];
      }
  outp[b * 1024 + t] = a;
}

extern "C" void kernel_launch(void* const* d_in, const int* in_sizes, int n_in,
                              void* d_out, int out_size, void* d_ws, size_t ws_size,
                              hipStream_t stream) {
  const float* x    = (const float*)d_in[0];
  const float* Wpc  = (const float*)d_in[1];
  const float* bpc  = (const float*)d_in[2];
  const float* Wpf  = (const float*)d_in[3];
  const float* bpf  = (const float*)d_in[4];
  const float* te   = (const float*)d_in[5];
  const float* ln1g = (const float*)d_in[6];
  const float* ln1b = (const float*)d_in[7];
  const float* Wqkv = (const float*)d_in[8];
  const float* Wo   = (const float*)d_in[9];
  const float* bo   = (const float*)d_in[10];
  const float* ln2g = (const float*)d_in[11];
  const float* ln2b = (const float*)d_in[12];
  const float* W1   = (const float*)d_in[13];
  const float* b1   = (const float*)d_in[14];
  const float* W2   = (const float*)d_in[15];
  const float* b2   = (const float*)d_in[16];
  const float* dWc  = (const float*)d_in[17];
  const float* dbc  = (const float*)d_in[18];
  const float* dWf  = (const float*)d_in[19];
  const float* dbf  = (const float*)d_in[20];
  const float* fW1  = (const float*)d_in[21];
  const float* fb1  = (const float*)d_in[22];
  const float* fW2  = (const float*)d_in[23];
  const float* fb2  = (const float*)d_in[24];

  char* ws = (char*)d_ws;
  float* tokens = (float*)ws;                 ws += 1310720 * 4;   // fp32 [B*N,128]
  short* ybuf   = (short*)ws;                 ws += 1310720 * 2;   // bf16
  short* qkvb   = (short*)ws;                 ws += 3932160 * 2;   // bf16 [B*N,384]
  short* obuf   = (short*)ws;                 ws += 1310720 * 2;   // bf16
  short* hbuf   = (short*)ws;                 ws += 2621440 * 2;   // bf16 [B*N,256]
  short* Opart  = (short*)ws;                 ws += (size_t)(Bx * HEADS * NQT * SPLIT) * 2048 * 2;
  float* Mpart  = (float*)ws;                 ws += (size_t)(Bx * HEADS * NQT * SPLIT) * 64 * 4;
  float* Lpart  = (float*)ws;                 ws += (size_t)(Bx * HEADS * NQT * SPLIT) * 64 * 4;
  short* WtQKV  = (short*)ws;                 ws += 98304 * 2;     // [L][384][128]
  short* WtO    = (short*)ws;                 ws += 32768 * 2;     // [L][128][128]
  short* Wt1    = (short*)ws;                 ws += 65536 * 2;     // [L][256][128]
  short* Wt2    = (short*)ws;                 ws += 65536 * 2;     // [L][128][256]
  float* msort  = (float*)ws;                 ws += 8192 * 4;
  float* c_up   = (float*)ws;                 ws += 8192 * 4;
  float* f_map  = (float*)ws;                 ws += 8192 * 4;
  int*   order  = (int*)ws;                   ws += 8192 * 4;
  int*   inv    = (int*)ws;                   ws += 8192 * 4;

  const int M = Bx * NTOK;                    // 10240

  k_prep_w<<<1024, 256, 0, stream>>>(Wqkv, Wo, W1, W2, WtQKV, WtO, Wt1, Wt2);
  k_coarse<<<Bx * NCc, 128, 0, stream>>>(x, Wpc, bpc, te, tokens);
  k_edge_sort<<<Bx, 1024, 0, stream>>>(x, order, inv, msort);
  k_fine<<<Bx * NFf, 128, 0, stream>>>(x, Wpf, bpf, te, inv, msort, tokens);

  for (int l = 0; l < LL; ++l) {
    k_ln_bf16<<<M / 4, 256, 0, stream>>>(tokens, ln1g + l * DD, ln1b + l * DD, ybuf);
    k_gemm_mfma<<<dim3(M / 64, 384 / 64), 256, 0, stream>>>(
        ybuf, WtQKV + (size_t)l * 49152, nullptr, nullptr, qkvb, 128, 384, 0);
    k_attn3<<<Bx * HEADS * NQT * SPLIT, 256, 0, stream>>>(qkvb, Opart, Mpart, Lpart);
    k_attn_combine<<<Bx * HEADS * NQT, 256, 0, stream>>>(Opart, Mpart, Lpart, obuf);
    k_gemm_mfma<<<dim3(M / 64, 128 / 64), 256, 0, stream>>>(
        obuf, WtO + (size_t)l * 16384, bo + l * DD, tokens, nullptr, 128, 128, 0);
    k_ln_bf16<<<M / 4, 256, 0, stream>>>(tokens, ln2g + l * DD, ln2b + l * DD, ybuf);
    k_gemm_mfma<<<dim3(M / 64, 256 / 64), 256, 0, stream>>>(
        ybuf, Wt1 + (size_t)l * 32768, b1 + l * 256, nullptr, hbuf, 128, 256, 1);
    k_gemm_mfma<<<dim3(M / 64, 128 / 64), 256, 0, stream>>>(
        hbuf, Wt2 + (size_t)l * 32768, b2 + l * DD, tokens, nullptr, 256, 128, 0);
  }

  k_coarse_dec<<<Bx, 1024, 0, stream>>>(tokens, dWc, dbc, c_up);
  k_fine_dec<<<Bx * NFf / 256, 256, 0, stream>>>(tokens, dWf, dbf, msort, order, f_map);
  k_fuse_conv<<<Bx, 1024, 0, stream>>>(c_up, f_map, fW1, fb1, fW2, fb2, (float*)d_out);
}

// Round 6
// 303.658 us; speedup vs baseline: 1.2214x; 1.0447x over previous
//
#include <hip/hip_runtime.h>
#include <math.h>

#define Bx 8
#define IMG 128
#define DD 128
#define HEADS 4
#define LL 2
#define PCc 8
#define PFf 4
#define HCc 16
#define NCc 256
#define HFf 32
#define NFf 1024
#define NTOK 1280
#define HD 32
#define SPLIT 4          // key-split factor for flash-decode attention
#define NQT 20           // NTOK/64 query tiles

typedef __attribute__((ext_vector_type(8))) short short8;
typedef __attribute__((ext_vector_type(4))) float f32x4;

__device__ __forceinline__ short f2bf(float f) {
  unsigned u = __builtin_bit_cast(unsigned, f);
  u += 0x7FFF + ((u >> 16) & 1);   // RNE
  return (short)(u >> 16);
}
__device__ __forceinline__ float bf2f(short s) {
  unsigned u = ((unsigned)(unsigned short)s) << 16;
  return __builtin_bit_cast(float, u);
}

// ---------------- coarse patch embed: tokens[:, :256] = patch@Wpc + bpc + te[0]
__global__ __launch_bounds__(128) void k_coarse(const float* __restrict__ x,
    const float* __restrict__ Wpc, const float* __restrict__ bpc,
    const float* __restrict__ te, float* __restrict__ tokens) {
  int blk = blockIdx.x;            // b*NC + t
  int b = blk / NCc, t = blk % NCc;
  int hc = t / HCc, wc = t % HCc;
  int d = threadIdx.x;
  __shared__ float patch[PCc * PCc];
  if (d < PCc * PCc) {
    int pi = d / PCc, pj = d % PCc;
    patch[d] = x[(b * IMG + hc * PCc + pi) * IMG + wc * PCc + pj];
  }
  __syncthreads();
  float acc = bpc[d] + te[d];
  #pragma unroll 8
  for (int i = 0; i < PCc * PCc; ++i) acc += patch[i] * Wpc[i * DD + d];
  tokens[(size_t)(b * NTOK + t) * DD + d] = acc;
}

// ---------------- sobel -> avgpool4 -> mask -> stable-sort order via ballot scan
__global__ __launch_bounds__(1024) void k_edge_sort(const float* __restrict__ x,
    int* __restrict__ order, int* __restrict__ inv, float* __restrict__ msort) {
  int b = blockIdx.x;
  int t = threadIdx.x;             // 0..1023 -> fine cell (fy,fx)
  int lane = t & 63, wave = t >> 6;
  int fy = t >> 5, fx = t & 31;
  const float* img = x + (size_t)b * IMG * IMG;
  float s = 0.f;
  for (int dy = 0; dy < 4; ++dy) {
    for (int dx = 0; dx < 4; ++dx) {
      int py = fy * 4 + dy, px = fx * 4 + dx;
      float v[3][3];
      #pragma unroll
      for (int ky = 0; ky < 3; ++ky)
        #pragma unroll
        for (int kx = 0; kx < 3; ++kx) {
          int yy = py + ky - 1, xx = px + kx - 1;
          v[ky][kx] = (yy >= 0 && yy < IMG && xx >= 0 && xx < IMG)
                          ? img[yy * IMG + xx] : 0.f;
        }
      float gx = -v[0][0] + v[0][2] - 2.f * v[1][0] + 2.f * v[1][2] - v[2][0] + v[2][2];
      float gy = -v[0][0] - 2.f * v[0][1] - v[0][2] + v[2][0] + 2.f * v[2][1] + v[2][2];
      s += sqrtf(gx * gx + gy * gy);
    }
  }
  float e = s * (1.f / 16.f);
  __shared__ float wsum[16];
  __shared__ int wcnt[16];
  float r = e;
  #pragma unroll
  for (int o = 32; o > 0; o >>= 1) r += __shfl_xor(r, o, 64);
  if (lane == 0) wsum[wave] = r;
  __syncthreads();
  float tot = 0.f;
  #pragma unroll
  for (int i = 0; i < 16; ++i) tot += wsum[i];
  float mean = tot * (1.f / 1024.f);
  int m = (e > mean) ? 1 : 0;
  unsigned long long bal = __ballot(m);
  if (lane == 0) wcnt[wave] = __popcll(bal);
  __syncthreads();
  int wbase = 0, total = 0;
  #pragma unroll
  for (int i = 0; i < 16; ++i) {
    int c = wcnt[i];
    if (i < wave) wbase += c;
    total += c;
  }
  unsigned long long below = (lane == 63) ? ~0ULL : ((1ULL << (lane + 1)) - 1);
  int incl = __popcll(bal & below);
  int eb = wbase + incl - m;       // edges strictly before t
  int pos = m ? eb : (total + t - eb);
  order[b * NFf + pos] = t;
  inv[b * NFf + t] = pos;
  msort[b * NFf + pos] = (float)m;
}

// ---------------- fine patch embed + direct scatter into tokens[:, 256:]
__global__ __launch_bounds__(128) void k_fine(const float* __restrict__ x,
    const float* __restrict__ Wpf, const float* __restrict__ bpf,
    const float* __restrict__ te, const int* __restrict__ inv,
    const float* __restrict__ msort, float* __restrict__ tokens) {
  int blk = blockIdx.x;            // b*NF + t
  int b = blk / NFf, t = blk % NFf;
  int hf = t / HFf, wf = t % HFf;
  int d = threadIdx.x;
  __shared__ float patch[PFf * PFf];
  if (d < PFf * PFf) {
    int pi = d / PFf, pj = d % PFf;
    patch[d] = x[(b * IMG + hf * PFf + pi) * IMG + wf * PFf + pj];
  }
  __syncthreads();
  float acc = bpf[d];
  #pragma unroll
  for (int i = 0; i < PFf * PFf; ++i) acc += patch[i] * Wpf[i * DD + d];
  int pos = inv[b * NFf + t];
  float mk = msort[b * NFf + pos];
  tokens[(size_t)(b * NTOK + NCc + pos) * DD + d] = acc * mk + te[DD + d];
}

// ---------------- weight prep: transpose + bf16 for all encoder GEMM weights
__global__ __launch_bounds__(256) void k_prep_w(const float* __restrict__ Wqkv,
    const float* __restrict__ Wo, const float* __restrict__ W1,
    const float* __restrict__ W2, short* __restrict__ WtQKV,
    short* __restrict__ WtO, short* __restrict__ Wt1, short* __restrict__ Wt2) {
  int idx = blockIdx.x * 256 + threadIdx.x;   // 0 .. 262143
  int l = idx / 131072, r = idx % 131072;
  const float* src; short* dst; int N, off;
  if (r < 49152)      { src = Wqkv + l * 49152; dst = WtQKV + l * 49152; N = 384; off = r; }
  else if (r < 65536) { src = Wo + l * 16384;  dst = WtO + l * 16384;  N = 128; off = r - 49152; }
  else if (r < 98304) { src = W1 + l * 32768;  dst = Wt1 + l * 32768;  N = 256; off = r - 65536; }
  else                { src = W2 + l * 32768;  dst = Wt2 + l * 32768;  N = 128; off = r - 98304; }
  int k = off / N, n = off % N;
  int K = (r >= 98304) ? 256 : 128;
  dst[(size_t)n * K + k] = f2bf(src[off]);
}

// ---------------- LayerNorm over D=128, one wave per row, out bf16
__global__ __launch_bounds__(256) void k_ln_bf16(const float* __restrict__ inp,
    const float* __restrict__ g, const float* __restrict__ bb,
    short* __restrict__ outp) {
  int row = blockIdx.x * 4 + (threadIdx.x >> 6);
  int lane = threadIdx.x & 63;
  float2 v = ((const float2*)(inp + (size_t)row * DD))[lane];
  float s = v.x + v.y;
  #pragma unroll
  for (int o = 32; o > 0; o >>= 1) s += __shfl_xor(s, o, 64);
  float mean = s * (1.f / 128.f);
  float cx = v.x - mean, cy = v.y - mean;
  float q = cx * cx + cy * cy;
  #pragma unroll
  for (int o = 32; o > 0; o >>= 1) q += __shfl_xor(q, o, 64);
  float rstd = rsqrtf(q * (1.f / 128.f) + 1e-5f);
  float2 gg = ((const float2*)g)[lane];
  float2 bv = ((const float2*)bb)[lane];
  int p = (int)(unsigned short)f2bf(cx * rstd * gg.x + bv.x)
        | ((int)(unsigned short)f2bf(cy * rstd * gg.y + bv.y) << 16);
  ((int*)(outp + (size_t)row * DD))[lane] = p;
}

// ---------------- MFMA GEMM with async global->LDS staging (m97 pattern)
// A bf16 [M,K], Wt bf16 [N][K]. Out: Cf fp32 += (residual) or Cb bf16 =.
// block 256 = 4 waves; tile 64 rows x 64 cols; K chunked at 128; LDS unpadded.
__global__ __launch_bounds__(256) void k_gemm_mfma(const short* __restrict__ A,
    const short* __restrict__ Wt, const float* __restrict__ bias,
    float* __restrict__ Cf, short* __restrict__ Cb, int K, int N, int do_gelu) {
  __shared__ short Alds[64 * 128];
  __shared__ short Blds[64 * 128];
  int row0 = blockIdx.x * 64, col0 = blockIdx.y * 64;
  int t = threadIdx.x;
  int lane = t & 63, w = t >> 6;
  int m = lane & 15, quad = lane >> 4;
  int lrow = lane >> 4, lcol = (lane & 15) * 8;   // staging sub-addressing
  f32x4 zero = {0.f, 0.f, 0.f, 0.f};
  f32x4 acc[4] = {zero, zero, zero, zero};

  for (int kb = 0; kb < K; kb += 128) {
    __syncthreads();
    #pragma unroll
    for (int j = 0; j < 4; ++j) {
      int c = j * 4 + w;               // chunk 0..15, wave-uniform
      __builtin_amdgcn_global_load_lds(
          (const unsigned*)&A[(size_t)(row0 + c * 4 + lrow) * K + kb + lcol],
          (unsigned*)&Alds[c * 512], 16, 0, 0);
      __builtin_amdgcn_global_load_lds(
          (const unsigned*)&Wt[(size_t)(col0 + c * 4 + lrow) * K + kb + lcol],
          (unsigned*)&Blds[c * 512], 16, 0, 0);
    }
    __syncthreads();
    const short* Abase = Alds + (w * 16 + m) * 128 + quad * 8;
    const short* Bbase = Blds + m * 128 + quad * 8;
    #pragma unroll
    for (int ks = 0; ks < 128; ks += 32) {
      short8 af = *(const short8*)(Abase + ks);
      #pragma unroll
      for (int nt = 0; nt < 4; ++nt) {
        short8 bf = *(const short8*)(Bbase + nt * 16 * 128 + ks);
        acc[nt] = __builtin_amdgcn_mfma_f32_16x16x32_bf16(af, bf, acc[nt], 0, 0, 0);
      }
    }
  }
  #pragma unroll
  for (int nt = 0; nt < 4; ++nt) {
    int col = col0 + nt * 16 + m;
    float bv = bias ? bias[col] : 0.f;
    #pragma unroll
    for (int r = 0; r < 4; ++r) {
      int row = row0 + w * 16 + quad * 4 + r;
      float v = acc[nt][r] + bv;
      if (do_gelu) v = 0.5f * v * (1.f + erff(v * 0.70710678118654752f));
      if (Cf) Cf[(size_t)row * N + col] += v;
      else    Cb[(size_t)row * N + col] = f2bf(v);
    }
  }
}

// ---------------- flash attention, split-K, fixed-max softmax (scores bounded:
// exp cannot overflow here, so softmax without max-sub is exact)
// grid = B*H*NQT*SPLIT; block = 256 (4 waves x 16 queries); 320 keys per block
__global__ __launch_bounds__(256) void k_attn4(const short* __restrict__ qkv,
    short* __restrict__ Opart, float* __restrict__ Lpart) {
  __shared__ short Ks[64 * 32];      // [key][d], filled via global_load_lds
  __shared__ short Vt[32 * 74];      // [d][key], stride 74 (2-way-free scatter)
  __shared__ short Pl[4][16 * 74];   // per-wave P [q][key]

  int sk = blockIdx.x % SPLIT;
  int qt = (blockIdx.x / SPLIT) % NQT;
  int h  = (blockIdx.x / (SPLIT * NQT)) % HEADS;
  int b  = blockIdx.x / (SPLIT * NQT * HEADS);
  int t = threadIdx.x;
  int lane = t & 63, w = t >> 6;
  int m = lane & 15, quad = lane >> 4;
  int q0 = qt * 64 + w * 16;

  const float scale = 0.17677669529663687f;  // 1/sqrt(32), folded into Q
  short8 qraw = *(const short8*)(qkv + ((size_t)(b * NTOK) + q0 + m) * 384 + h * HD + quad * 8);
  short8 qf;
  #pragma unroll
  for (int j = 0; j < 8; ++j) qf[j] = f2bf(bf2f(qraw[j]) * scale);

  f32x4 zero = {0.f, 0.f, 0.f, 0.f};
  f32x4 Oacc[2] = {zero, zero};
  float psum[4] = {0.f, 0.f, 0.f, 0.f};

  int skey = t >> 2, sdseg = t & 3;  // staging: key 0..63, 8 dims each
  const short* kstage = qkv + ((size_t)(b * NTOK) + skey) * 384 + 128 + h * HD + sdseg * 8;

  for (int s = sk * 5; s < sk * 5 + 5; ++s) {
    __syncthreads();
    // K tile: async DMA (lane order t*16B matches [key][d] layout exactly)
    __builtin_amdgcn_global_load_lds((const unsigned*)(kstage + (size_t)s * 64 * 384),
                                     (unsigned*)&Ks[w * 512], 16, 0, 0);
    // V tile: transpose scatter (2 lanes/bank -> free)
    short8 vf = *(const short8*)(kstage + 128 + (size_t)s * 64 * 384);
    #pragma unroll
    for (int j = 0; j < 8; ++j) Vt[(sdseg * 8 + j) * 74 + skey] = vf[j];
    __syncthreads();

    // S = Q K^T (C-layout: row=4*quad+reg, col=m); Q pre-scaled
    f32x4 sc[4];
    #pragma unroll
    for (int ct = 0; ct < 4; ++ct) {
      short8 kfrag = *(const short8*)&Ks[(ct * 16 + m) * 32 + quad * 8];
      sc[ct] = __builtin_amdgcn_mfma_f32_16x16x32_bf16(qf, kfrag, zero, 0, 0, 0);
    }
    // fixed-max softmax: p = exp(s); l accumulated from TRUNCATED p (bias-free)
    #pragma unroll
    for (int ct = 0; ct < 4; ++ct)
      #pragma unroll
      for (int r = 0; r < 4; ++r) {
        float p = __expf(sc[ct][r]);
        unsigned u = __builtin_bit_cast(unsigned, p);
        psum[r] += __builtin_bit_cast(float, u & 0xffff0000u);
        Pl[w][(quad * 4 + r) * 74 + ct * 16 + m] = (short)(u >> 16);
      }
    // O += P @ V (no rescale needed)
    #pragma unroll
    for (int ks = 0; ks < 2; ++ks) {
      short8 pfrag = *(const short8*)&Pl[w][m * 74 + ks * 32 + quad * 8];
      #pragma unroll
      for (int nt = 0; nt < 2; ++nt) {
        short8 vfrag = *(const short8*)&Vt[(nt * 16 + m) * 74 + ks * 32 + quad * 8];
        Oacc[nt] = __builtin_amdgcn_mfma_f32_16x16x32_bf16(pfrag, vfrag, Oacc[nt], 0, 0, 0);
      }
    }
  }
  // single final ladder per row; write partial O (unnormalized) + l
  #pragma unroll
  for (int r = 0; r < 4; ++r) {
    float ssum = psum[r];
    #pragma unroll
    for (int o = 1; o < 16; o <<= 1) ssum += __shfl_xor(ssum, o);
    int qloc = w * 16 + quad * 4 + r;
    #pragma unroll
    for (int nt = 0; nt < 2; ++nt)
      Opart[(size_t)blockIdx.x * 2048 + qloc * 32 + nt * 16 + m] = f2bf(Oacc[nt][r]);
    if (m == 0) Lpart[(size_t)blockIdx.x * 64 + qloc] = ssum;
  }
}

// ---------------- combine split-K partials (plain sum; fixed max) -> obuf bf16
__global__ __launch_bounds__(256) void k_attn_combine(const short* __restrict__ Opart,
    const float* __restrict__ Lpart, short* __restrict__ obuf) {
  int blk = blockIdx.x;
  int qt = blk % NQT, h = (blk / NQT) % HEADS, b = blk / (NQT * HEADS);
  int t = threadIdx.x;
  int q = t >> 2, seg = t & 3;
  size_t pbase = (size_t)blk * SPLIT;
  float L = 0.f;
  #pragma unroll
  for (int sk = 0; sk < SPLIT; ++sk) L += Lpart[(pbase + sk) * 64 + q];
  float o[8] = {0, 0, 0, 0, 0, 0, 0, 0};
  #pragma unroll
  for (int sk = 0; sk < SPLIT; ++sk) {
    short8 po = *(const short8*)&Opart[(pbase + sk) * 2048 + q * 32 + seg * 8];
    #pragma unroll
    for (int j = 0; j < 8; ++j) o[j] += bf2f(po[j]);
  }
  float rs = 1.f / L;
  short8 ov;
  #pragma unroll
  for (int j = 0; j < 8; ++j) ov[j] = f2bf(o[j] * rs);
  *(short8*)&obuf[(size_t)(b * NTOK + qt * 64 + q) * DD + h * HD + seg * 8] = ov;
}

// ---------------- coarse decoder head + 16->32 align-corners bilinear
__global__ __launch_bounds__(1024) void k_coarse_dec(const float* __restrict__ tokens,
    const float* __restrict__ dWc, const float* __restrict__ dbc,
    float* __restrict__ c_up) {
  int b = blockIdx.x;
  int t = threadIdx.x;
  __shared__ float c[NCc];
  if (t < NCc) {
    const float* row = tokens + (size_t)(b * NTOK + t) * DD;
    float a = 0.f;
    for (int d = 0; d < DD; ++d) a += row[d] * dWc[d];
    c[t] = a + dbc[0];
  }
  __syncthreads();
  int oy = t >> 5, ox = t & 31;
  float ys = oy * (15.f / 31.f);
  float xs = ox * (15.f / 31.f);
  int y0 = (int)floorf(ys); int y1 = min(y0 + 1, 15); float wy = ys - (float)y0;
  int x0 = (int)floorf(xs); int x1 = min(x0 + 1, 15); float wx = xs - (float)x0;
  float v = c[y0 * 16 + x0] * (1.f - wy) * (1.f - wx)
          + c[y0 * 16 + x1] * (1.f - wy) * wx
          + c[y1 * 16 + x0] * wy * (1.f - wx)
          + c[y1 * 16 + x1] * wy * wx;
  c_up[b * 1024 + t] = v;
}

// ---------------- fine decoder head, mask, scatter back to pixel order
__global__ __launch_bounds__(256) void k_fine_dec(const float* __restrict__ tokens,
    const float* __restrict__ dWf, const float* __restrict__ dbf,
    const float* __restrict__ msort, const int* __restrict__ order,
    float* __restrict__ f_map) {
  int idx = blockIdx.x * 256 + threadIdx.x;  // b*NF + j
  int b = idx >> 10, j = idx & 1023;
  const float* row = tokens + (size_t)(b * NTOK + NCc + j) * DD;
  float a = 0.f;
  for (int d = 0; d < DD; ++d) a += row[d] * dWf[d];
  a = (a + dbf[0]) * msort[b * NFf + j];
  f_map[b * NFf + order[b * NFf + j]] = a;  // 32->32 AC-bilinear is identity
}

// ---------------- fused 2-ch conv3x3 + relu + conv3x3 -> out
__global__ __launch_bounds__(1024) void k_fuse_conv(const float* __restrict__ c_up,
    const float* __restrict__ f_map, const float* __restrict__ fW1,
    const float* __restrict__ fb1, const float* __restrict__ fW2,
    const float* __restrict__ fb2, float* __restrict__ outp) {
  int b = blockIdx.x;
  int t = threadIdx.x;
  int y = t >> 5, x = t & 31;
  __shared__ float fin[2][1024];
  __shared__ float hb[2][1024];
  fin[0][t] = c_up[b * 1024 + t];
  fin[1][t] = f_map[b * 1024 + t];
  __syncthreads();
  for (int oc = 0; oc < 2; ++oc) {
    float a = fb1[oc];
    #pragma unroll
    for (int ic = 0; ic < 2; ++ic)
      #pragma unroll
      for (int ky = 0; ky < 3; ++ky)
        #pragma unroll
        for (int kx = 0; kx < 3; ++kx) {
          int yy = y + ky - 1, xx = x + kx - 1;
          float v = (yy >= 0 && yy < 32 && xx >= 0 && xx < 32)
                        ? fin[ic][yy * 32 + xx] : 0.f;
          a += v * fW1[((oc * 2 + ic) * 3 + ky) * 3 + kx];
        }
    hb[oc][t] = fmaxf(a, 0.f);
  }
  __syncthreads();
  float a = fb2[0];
  #pragma unroll
  for (int ic = 0; ic < 2; ++ic)
    #pragma unroll
    for (int ky = 0; ky < 3; ++ky)
      #pragma unroll
      for (int kx = 0; kx < 3; ++kx) {
        int yy = y + ky - 1, xx = x + kx - 1;
        float v = (yy >= 0 && yy < 32 && xx >= 0 && xx < 32)
                      ? hb[ic][yy * 32 + xx] : 0.f;
        a += v * fW2[(ic * 3 + ky) * 3 + kx];
      }
  outp[b * 1024 + t] = a;
}

extern "C" void kernel_launch(void* const* d_in, const int* in_sizes, int n_in,
                              void* d_out, int out_size, void* d_ws, size_t ws_size,
                              hipStream_t stream) {
  const float* x    = (const float*)d_in[0];
  const float* Wpc  = (const float*)d_in[1];
  const float* bpc  = (const float*)d_in[2];
  const float* Wpf  = (const float*)d_in[3];
  const float* bpf  = (const float*)d_in[4];
  const float* te   = (const float*)d_in[5];
  const float* ln1g = (const float*)d_in[6];
  const float* ln1b = (const float*)d_in[7];
  const float* Wqkv = (const float*)d_in[8];
  const float* Wo   = (const float*)d_in[9];
  const float* bo   = (const float*)d_in[10];
  const float* ln2g = (const float*)d_in[11];
  const float* ln2b = (const float*)d_in[12];
  const float* W1   = (const float*)d_in[13];
  const float* b1   = (const float*)d_in[14];
  const float* W2   = (const float*)d_in[15];
  const float* b2   = (const float*)d_in[16];
  const float* dWc  = (const float*)d_in[17];
  const float* dbc  = (const float*)d_in[18];
  const float* dWf  = (const float*)d_in[19];
  const float* dbf  = (const float*)d_in[20];
  const float* fW1  = (const float*)d_in[21];
  const float* fb1  = (const float*)d_in[22];
  const float* fW2  = (const float*)d_in[23];
  const float* fb2  = (const float*)d_in[24];

  char* ws = (char*)d_ws;
  float* tokens = (float*)ws;                 ws += 1310720 * 4;   // fp32 [B*N,128]
  short* ybuf   = (short*)ws;                 ws += 1310720 * 2;   // bf16
  short* qkvb   = (short*)ws;                 ws += 3932160 * 2;   // bf16 [B*N,384]
  short* obuf   = (short*)ws;                 ws += 1310720 * 2;   // bf16
  short* hbuf   = (short*)ws;                 ws += 2621440 * 2;   // bf16 [B*N,256]
  short* Opart  = (short*)ws;                 ws += (size_t)(Bx * HEADS * NQT * SPLIT) * 2048 * 2;
  float* Lpart  = (float*)ws;                 ws += (size_t)(Bx * HEADS * NQT * SPLIT) * 64 * 4;
  short* WtQKV  = (short*)ws;                 ws += 98304 * 2;     // [L][384][128]
  short* WtO    = (short*)ws;                 ws += 32768 * 2;     // [L][128][128]
  short* Wt1    = (short*)ws;                 ws += 65536 * 2;     // [L][256][128]
  short* Wt2    = (short*)ws;                 ws += 65536 * 2;     // [L][128][256]
  float* msort  = (float*)ws;                 ws += 8192 * 4;
  float* c_up   = (float*)ws;                 ws += 8192 * 4;
  float* f_map  = (float*)ws;                 ws += 8192 * 4;
  int*   order  = (int*)ws;                   ws += 8192 * 4;
  int*   inv    = (int*)ws;                   ws += 8192 * 4;

  const int M = Bx * NTOK;                    // 10240

  k_prep_w<<<1024, 256, 0, stream>>>(Wqkv, Wo, W1, W2, WtQKV, WtO, Wt1, Wt2);
  k_coarse<<<Bx * NCc, 128, 0, stream>>>(x, Wpc, bpc, te, tokens);
  k_edge_sort<<<Bx, 1024, 0, stream>>>(x, order, inv, msort);
  k_fine<<<Bx * NFf, 128, 0, stream>>>(x, Wpf, bpf, te, inv, msort, tokens);

  for (int l = 0; l < LL; ++l) {
    k_ln_bf16<<<M / 4, 256, 0, stream>>>(tokens, ln1g + l * DD, ln1b + l * DD, ybuf);
    k_gemm_mfma<<<dim3(M / 64, 384 / 64), 256, 0, stream>>>(
        ybuf, WtQKV + (size_t)l * 49152, nullptr, nullptr, qkvb, 128, 384, 0);
    k_attn4<<<Bx * HEADS * NQT * SPLIT, 256, 0, stream>>>(qkvb, Opart, Lpart);
    k_attn_combine<<<Bx * HEADS * NQT, 256, 0, stream>>>(Opart, Lpart, obuf);
    k_gemm_mfma<<<dim3(M / 64, 128 / 64), 256, 0, stream>>>(
        obuf, WtO + (size_t)l * 16384, bo + l * DD, tokens, nullptr, 128, 128, 0);
    k_ln_bf16<<<M / 4, 256, 0, stream>>>(tokens, ln2g + l * DD, ln2b + l * DD, ybuf);
    k_gemm_mfma<<<dim3(M / 64, 256 / 64), 256, 0, stream>>>(
        ybuf, Wt1 + (size_t)l * 32768, b1 + l * 256, nullptr, hbuf, 128, 256, 1);
    k_gemm_mfma<<<dim3(M / 64, 128 / 64), 256, 0, stream>>>(
        hbuf, Wt2 + (size_t)l * 32768, b2 + l * DD, tokens, nullptr, 256, 128, 0);
  }

  k_coarse_dec<<<Bx, 1024, 0, stream>>>(tokens, dWc, dbc, c_up);
  k_fine_dec<<<Bx * NFf / 256, 256, 0, stream>>>(tokens, dWf, dbf, msort, order, f_map);
  k_fuse_conv<<<Bx, 1024, 0, stream>>>(c_up, f_map, fW1, fb1, fW2, fb2, (float*)d_out);
}

// Round 7
// 258.126 us; speedup vs baseline: 1.4368x; 1.1764x over previous
//
#include <hip/hip_runtime.h>
#include <math.h>

#define Bx 8
#define IMG 128
#define DD 128
#define HEADS 4
#define LL 2
#define PCc 8
#define PFf 4
#define HCc 16
#define NCc 256
#define HFf 32
#define NFf 1024
#define NTOK 1280
#define HD 32
#define SPLIT 4          // key-split factor for flash-decode attention
#define NQT 20           // NTOK/64 query tiles

typedef __attribute__((ext_vector_type(8))) short short8;
typedef __attribute__((ext_vector_type(4))) float f32x4;

__device__ __forceinline__ short f2bf(float f) {
  unsigned u = __builtin_bit_cast(unsigned, f);
  u += 0x7FFF + ((u >> 16) & 1);   // RNE
  return (short)(u >> 16);
}
__device__ __forceinline__ float bf2f(short s) {
  unsigned u = ((unsigned)(unsigned short)s) << 16;
  return __builtin_bit_cast(float, u);
}

// ---------------- coarse patch embed: tokens[:, :256] = patch@Wpc + bpc + te[0]
__global__ __launch_bounds__(128) void k_coarse(const float* __restrict__ x,
    const float* __restrict__ Wpc, const float* __restrict__ bpc,
    const float* __restrict__ te, float* __restrict__ tokens) {
  int blk = blockIdx.x;            // b*NC + t
  int b = blk / NCc, t = blk % NCc;
  int hc = t / HCc, wc = t % HCc;
  int d = threadIdx.x;
  __shared__ float patch[PCc * PCc];
  if (d < PCc * PCc) {
    int pi = d / PCc, pj = d % PCc;
    patch[d] = x[(b * IMG + hc * PCc + pi) * IMG + wc * PCc + pj];
  }
  __syncthreads();
  float acc = bpc[d] + te[d];
  #pragma unroll 8
  for (int i = 0; i < PCc * PCc; ++i) acc += patch[i] * Wpc[i * DD + d];
  tokens[(size_t)(b * NTOK + t) * DD + d] = acc;
}

// ---------------- sobel + 4x4 avgpool -> cell energy e[b][1024]
// grid = Bx*64 (16x16-px tiles), block 256 = 1 px/thread
__global__ __launch_bounds__(256) void k_sobel(const float* __restrict__ x,
    float* __restrict__ e) {
  int blk = blockIdx.x;
  int b = blk >> 6, tile = blk & 63;
  int ty = tile >> 3, tx = tile & 7;
  int t = threadIdx.x;
  int ly = t >> 4, lx = t & 15;
  int py = ty * 16 + ly, px = tx * 16 + lx;
  const float* img = x + (size_t)b * IMG * IMG;
  float v[3][3];
  #pragma unroll
  for (int ky = 0; ky < 3; ++ky)
    #pragma unroll
    for (int kx = 0; kx < 3; ++kx) {
      int yy = py + ky - 1, xx = px + kx - 1;
      v[ky][kx] = (yy >= 0 && yy < IMG && xx >= 0 && xx < IMG)
                      ? img[yy * IMG + xx] : 0.f;
    }
  float gx = -v[0][0] + v[0][2] - 2.f * v[1][0] + 2.f * v[1][2] - v[2][0] + v[2][2];
  float gy = -v[0][0] - 2.f * v[0][1] - v[0][2] + v[2][0] + 2.f * v[2][1] + v[2][2];
  __shared__ float sm[256];
  sm[t] = sqrtf(gx * gx + gy * gy);
  __syncthreads();
  if (t < 16) {                       // 16 cells of 4x4 px per tile
    int cy = t >> 2, cx = t & 3;
    float s = 0.f;
    #pragma unroll
    for (int dy = 0; dy < 4; ++dy)
      #pragma unroll
      for (int dx = 0; dx < 4; ++dx) s += sm[(cy * 4 + dy) * 16 + cx * 4 + dx];
    e[b * NFf + (ty * 4 + cy) * 32 + tx * 4 + cx] = s * (1.f / 16.f);
  }
}

// ---------------- mask at per-image mean -> stable-sort order via ballot scan
__global__ __launch_bounds__(1024) void k_edge_sort(const float* __restrict__ e,
    int* __restrict__ order, int* __restrict__ inv, float* __restrict__ msort) {
  int b = blockIdx.x;
  int t = threadIdx.x;
  int lane = t & 63, wave = t >> 6;
  float ev = e[b * NFf + t];
  __shared__ float wsum[16];
  __shared__ int wcnt[16];
  float r = ev;
  #pragma unroll
  for (int o = 32; o > 0; o >>= 1) r += __shfl_xor(r, o, 64);
  if (lane == 0) wsum[wave] = r;
  __syncthreads();
  float tot = 0.f;
  #pragma unroll
  for (int i = 0; i < 16; ++i) tot += wsum[i];
  float mean = tot * (1.f / 1024.f);
  int m = (ev > mean) ? 1 : 0;
  unsigned long long bal = __ballot(m);
  if (lane == 0) wcnt[wave] = __popcll(bal);
  __syncthreads();
  int wbase = 0, total = 0;
  #pragma unroll
  for (int i = 0; i < 16; ++i) {
    int c = wcnt[i];
    if (i < wave) wbase += c;
    total += c;
  }
  unsigned long long below = (lane == 63) ? ~0ULL : ((1ULL << (lane + 1)) - 1);
  int incl = __popcll(bal & below);
  int eb = wbase + incl - m;       // edges strictly before t
  int pos = m ? eb : (total + t - eb);
  order[b * NFf + pos] = t;
  inv[b * NFf + t] = pos;
  msort[b * NFf + pos] = (float)m;
}

// ---------------- fine patch embed + direct scatter into tokens[:, 256:]
__global__ __launch_bounds__(128) void k_fine(const float* __restrict__ x,
    const float* __restrict__ Wpf, const float* __restrict__ bpf,
    const float* __restrict__ te, const int* __restrict__ inv,
    const float* __restrict__ msort, float* __restrict__ tokens) {
  int blk = blockIdx.x;            // b*NF + t
  int b = blk / NFf, t = blk % NFf;
  int hf = t / HFf, wf = t % HFf;
  int d = threadIdx.x;
  __shared__ float patch[PFf * PFf];
  if (d < PFf * PFf) {
    int pi = d / PFf, pj = d % PFf;
    patch[d] = x[(b * IMG + hf * PFf + pi) * IMG + wf * PFf + pj];
  }
  __syncthreads();
  float acc = bpf[d];
  #pragma unroll
  for (int i = 0; i < PFf * PFf; ++i) acc += patch[i] * Wpf[i * DD + d];
  int pos = inv[b * NFf + t];
  float mk = msort[b * NFf + pos];
  tokens[(size_t)(b * NTOK + NCc + pos) * DD + d] = acc * mk + te[DD + d];
}

// ---------------- weight prep: transpose + bf16 for all encoder GEMM weights
__global__ __launch_bounds__(256) void k_prep_w(const float* __restrict__ Wqkv,
    const float* __restrict__ Wo, const float* __restrict__ W1,
    const float* __restrict__ W2, short* __restrict__ WtQKV,
    short* __restrict__ WtO, short* __restrict__ Wt1, short* __restrict__ Wt2) {
  int idx = blockIdx.x * 256 + threadIdx.x;   // 0 .. 262143
  int l = idx / 131072, r = idx % 131072;
  const float* src; short* dst; int N, off;
  if (r < 49152)      { src = Wqkv + l * 49152; dst = WtQKV + l * 49152; N = 384; off = r; }
  else if (r < 65536) { src = Wo + l * 16384;  dst = WtO + l * 16384;  N = 128; off = r - 49152; }
  else if (r < 98304) { src = W1 + l * 32768;  dst = Wt1 + l * 32768;  N = 256; off = r - 65536; }
  else                { src = W2 + l * 32768;  dst = Wt2 + l * 32768;  N = 128; off = r - 98304; }
  int k = off / N, n = off % N;
  int K = (r >= 98304) ? 256 : 128;
  dst[(size_t)n * K + k] = f2bf(src[off]);
}

// ---------------- LayerNorm over D=128, one wave per row, out bf16
__global__ __launch_bounds__(256) void k_ln_bf16(const float* __restrict__ inp,
    const float* __restrict__ g, const float* __restrict__ bb,
    short* __restrict__ outp) {
  int row = blockIdx.x * 4 + (threadIdx.x >> 6);
  int lane = threadIdx.x & 63;
  float2 v = ((const float2*)(inp + (size_t)row * DD))[lane];
  float s = v.x + v.y;
  #pragma unroll
  for (int o = 32; o > 0; o >>= 1) s += __shfl_xor(s, o, 64);
  float mean = s * (1.f / 128.f);
  float cx = v.x - mean, cy = v.y - mean;
  float q = cx * cx + cy * cy;
  #pragma unroll
  for (int o = 32; o > 0; o >>= 1) q += __shfl_xor(q, o, 64);
  float rstd = rsqrtf(q * (1.f / 128.f) + 1e-5f);
  float2 gg = ((const float2*)g)[lane];
  float2 bv = ((const float2*)bb)[lane];
  int p = (int)(unsigned short)f2bf(cx * rstd * gg.x + bv.x)
        | ((int)(unsigned short)f2bf(cy * rstd * gg.y + bv.y) << 16);
  ((int*)(outp + (size_t)row * DD))[lane] = p;
}

// ---------------- MFMA GEMM, async DMA staging with XOR-swizzled LDS layout
// logical chunk j of tile-row r lives at physical chunk j^(r&15); fragment reads
// hit 16 distinct chunks per quad-group -> <=2-way bank aliasing (free).
__global__ __launch_bounds__(256) void k_gemm_mfma(const short* __restrict__ A,
    const short* __restrict__ Wt, const float* __restrict__ bias,
    float* __restrict__ Cf, short* __restrict__ Cb, int K, int N, int do_gelu) {
  __shared__ short Alds[64 * 128];
  __shared__ short Blds[64 * 128];
  int row0 = blockIdx.x * 64, col0 = blockIdx.y * 64;
  int t = threadIdx.x;
  int lane = t & 63, w = t >> 6;
  int m = lane & 15, quad = lane >> 4;
  int lrow = lane >> 4, jphys = lane & 15;   // staging sub-addressing
  f32x4 zero = {0.f, 0.f, 0.f, 0.f};
  f32x4 acc[4] = {zero, zero, zero, zero};

  for (int kb = 0; kb < K; kb += 128) {
    __syncthreads();
    #pragma unroll
    for (int j = 0; j < 4; ++j) {
      int c = j * 4 + w;               // chunk-group 0..15, wave-uniform
      int r = c * 4 + lrow;            // tile row this lane fetches
      int jlog = jphys ^ (r & 15);     // XOR swizzle
      __builtin_amdgcn_global_load_lds(
          (const unsigned*)&A[(size_t)(row0 + r) * K + kb + jlog * 8],
          (unsigned*)&Alds[c * 512], 16, 0, 0);
      __builtin_amdgcn_global_load_lds(
          (const unsigned*)&Wt[(size_t)(col0 + r) * K + kb + jlog * 8],
          (unsigned*)&Blds[c * 512], 16, 0, 0);
    }
    __syncthreads();
    #pragma unroll
    for (int ks = 0; ks < 4; ++ks) {   // logical chunk = quad + ks*4
      int pc = ((quad + ks * 4) ^ m) * 8;
      short8 af = *(const short8*)&Alds[(w * 16 + m) * 128 + pc];
      #pragma unroll
      for (int nt = 0; nt < 4; ++nt) {
        short8 bf = *(const short8*)&Blds[(nt * 16 + m) * 128 + pc];
        acc[nt] = __builtin_amdgcn_mfma_f32_16x16x32_bf16(af, bf, acc[nt], 0, 0, 0);
      }
    }
  }
  #pragma unroll
  for (int nt = 0; nt < 4; ++nt) {
    int col = col0 + nt * 16 + m;
    float bv = bias ? bias[col] : 0.f;
    #pragma unroll
    for (int r = 0; r < 4; ++r) {
      int row = row0 + w * 16 + quad * 4 + r;
      float v = acc[nt][r] + bv;
      if (do_gelu) v = 0.5f * v * (1.f + erff(v * 0.70710678118654752f));
      if (Cf) Cf[(size_t)row * N + col] += v;
      else    Cb[(size_t)row * N + col] = f2bf(v);
    }
  }
}

// ---------------- Wo GEMM with fused split-K combine: A staged directly from
// Opart/Lpart (the 64 A-rows of a block are exactly one (b,qt) attention tile).
// A: padded 136 stride (VALU write). B: DMA + XOR swizzle. Out: tokens fp32 +=.
__global__ __launch_bounds__(256) void k_gemm_wo(const short* __restrict__ Opart,
    const float* __restrict__ Lpart, const short* __restrict__ Wt,
    const float* __restrict__ bias, float* __restrict__ Cf) {
  __shared__ short Alds[64 * 136];
  __shared__ short Blds[64 * 128];
  int row0 = blockIdx.x * 64, col0 = blockIdx.y * 64;
  int b = row0 / NTOK, qt = (row0 / 64) % NQT;
  int t = threadIdx.x;
  int lane = t & 63, w = t >> 6;
  int m = lane & 15, quad = lane >> 4;
  int lrow = lane >> 4, jphys = lane & 15;
  f32x4 zero = {0.f, 0.f, 0.f, 0.f};
  f32x4 acc[4] = {zero, zero, zero, zero};

  // ---- A staging: combine 4 split-K partials, normalize by L, write bf16
  #pragma unroll
  for (int it = 0; it < 4; ++it) {
    int idx = t + it * 256;            // 1024 short8 chunks
    int q = idx >> 4, j = idx & 15;
    int hh = j >> 2, dd = (j & 3) * 8;
    size_t pb = ((size_t)(b * HEADS + hh) * NQT + qt) * SPLIT;
    float L = Lpart[(pb + 0) * 64 + q] + Lpart[(pb + 1) * 64 + q]
            + Lpart[(pb + 2) * 64 + q] + Lpart[(pb + 3) * 64 + q];
    float o[8] = {0, 0, 0, 0, 0, 0, 0, 0};
    #pragma unroll
    for (int sk = 0; sk < SPLIT; ++sk) {
      short8 po = *(const short8*)&Opart[(pb + sk) * 2048 + q * 32 + dd];
      #pragma unroll
      for (int i = 0; i < 8; ++i) o[i] += bf2f(po[i]);
    }
    float rs = 1.f / L;
    short8 ov;
    #pragma unroll
    for (int i = 0; i < 8; ++i) ov[i] = f2bf(o[i] * rs);
    *(short8*)&Alds[q * 136 + j * 8] = ov;
  }
  // ---- B staging: DMA + swizzle
  #pragma unroll
  for (int j = 0; j < 4; ++j) {
    int c = j * 4 + w;
    int r = c * 4 + lrow;
    int jlog = jphys ^ (r & 15);
    __builtin_amdgcn_global_load_lds(
        (const unsigned*)&Wt[(size_t)(col0 + r) * 128 + jlog * 8],
        (unsigned*)&Blds[c * 512], 16, 0, 0);
  }
  __syncthreads();
  #pragma unroll
  for (int ks = 0; ks < 4; ++ks) {
    short8 af = *(const short8*)&Alds[(w * 16 + m) * 136 + quad * 8 + ks * 32];
    int pc = ((quad + ks * 4) ^ m) * 8;
    #pragma unroll
    for (int nt = 0; nt < 4; ++nt) {
      short8 bf = *(const short8*)&Blds[(nt * 16 + m) * 128 + pc];
      acc[nt] = __builtin_amdgcn_mfma_f32_16x16x32_bf16(af, bf, acc[nt], 0, 0, 0);
    }
  }
  #pragma unroll
  for (int nt = 0; nt < 4; ++nt) {
    int col = col0 + nt * 16 + m;
    float bv = bias[col];
    #pragma unroll
    for (int r = 0; r < 4; ++r) {
      int row = row0 + w * 16 + quad * 4 + r;
      Cf[(size_t)row * DD + col] += acc[nt][r] + bv;
    }
  }
}

// ---------------- flash attention, split-K, fixed-max softmax, swizzled Ks
// grid = B*H*NQT*SPLIT; block = 256 (4 waves x 16 queries); 320 keys per block
__global__ __launch_bounds__(256) void k_attn4(const short* __restrict__ qkv,
    short* __restrict__ Opart, float* __restrict__ Lpart) {
  __shared__ short Ks[64 * 32];      // [key][d], DMA, chunk swizzle f(k)=(k>>1)&3
  __shared__ short Vt[32 * 74];      // [d][key], stride 74 (free scatter+gather)
  __shared__ short Pl[4][16 * 74];   // per-wave P [q][key]

  int sk = blockIdx.x % SPLIT;
  int qt = (blockIdx.x / SPLIT) % NQT;
  int h  = (blockIdx.x / (SPLIT * NQT)) % HEADS;
  int b  = blockIdx.x / (SPLIT * NQT * HEADS);
  int t = threadIdx.x;
  int lane = t & 63, w = t >> 6;
  int m = lane & 15, quad = lane >> 4;
  int q0 = qt * 64 + w * 16;

  const float scale = 0.17677669529663687f;  // 1/sqrt(32), folded into Q
  short8 qraw = *(const short8*)(qkv + ((size_t)(b * NTOK) + q0 + m) * 384 + h * HD + quad * 8);
  short8 qf;
  #pragma unroll
  for (int j = 0; j < 8; ++j) qf[j] = f2bf(bf2f(qraw[j]) * scale);

  f32x4 zero = {0.f, 0.f, 0.f, 0.f};
  f32x4 Oacc[2] = {zero, zero};
  float psum[4] = {0.f, 0.f, 0.f, 0.f};

  int skey = t >> 2, sdseg = t & 3;  // staging: key 0..63, 8 dims each
  // K fetch with XOR-swizzled chunk so ds_read hits spread banks
  int jlogK = sdseg ^ ((skey >> 1) & 3);
  const short* kstage = qkv + ((size_t)(b * NTOK) + skey) * 384 + 128 + h * HD + jlogK * 8;
  const short* vstage = qkv + ((size_t)(b * NTOK) + skey) * 384 + 256 + h * HD + sdseg * 8;
  int kswz = (quad ^ ((m >> 1) & 3)) * 8;   // read-side physical chunk offset

  for (int s = sk * 5; s < sk * 5 + 5; ++s) {
    __syncthreads();
    __builtin_amdgcn_global_load_lds((const unsigned*)(kstage + (size_t)s * 64 * 384),
                                     (unsigned*)&Ks[w * 512], 16, 0, 0);
    short8 vf = *(const short8*)(vstage + (size_t)s * 64 * 384);
    #pragma unroll
    for (int j = 0; j < 8; ++j) Vt[(sdseg * 8 + j) * 74 + skey] = vf[j];
    __syncthreads();

    // S = Q K^T (C-layout: row=4*quad+reg, col=m); Q pre-scaled
    f32x4 sc[4];
    #pragma unroll
    for (int ct = 0; ct < 4; ++ct) {
      short8 kfrag = *(const short8*)&Ks[(ct * 16 + m) * 32 + kswz];
      sc[ct] = __builtin_amdgcn_mfma_f32_16x16x32_bf16(qf, kfrag, zero, 0, 0, 0);
    }
    // fixed-max softmax: p = exp(s); l accumulated from TRUNCATED p (bias-free)
    #pragma unroll
    for (int ct = 0; ct < 4; ++ct)
      #pragma unroll
      for (int r = 0; r < 4; ++r) {
        float p = __expf(sc[ct][r]);
        unsigned u = __builtin_bit_cast(unsigned, p);
        psum[r] += __builtin_bit_cast(float, u & 0xffff0000u);
        Pl[w][(quad * 4 + r) * 74 + ct * 16 + m] = (short)(u >> 16);
      }
    // O += P @ V
    #pragma unroll
    for (int ks = 0; ks < 2; ++ks) {
      short8 pfrag = *(const short8*)&Pl[w][m * 74 + ks * 32 + quad * 8];
      #pragma unroll
      for (int nt = 0; nt < 2; ++nt) {
        short8 vfrag = *(const short8*)&Vt[(nt * 16 + m) * 74 + ks * 32 + quad * 8];
        Oacc[nt] = __builtin_amdgcn_mfma_f32_16x16x32_bf16(pfrag, vfrag, Oacc[nt], 0, 0, 0);
      }
    }
  }
  // single final ladder per row; write partial O (unnormalized) + l
  #pragma unroll
  for (int r = 0; r < 4; ++r) {
    float ssum = psum[r];
    #pragma unroll
    for (int o = 1; o < 16; o <<= 1) ssum += __shfl_xor(ssum, o);
    int qloc = w * 16 + quad * 4 + r;
    #pragma unroll
    for (int nt = 0; nt < 2; ++nt)
      Opart[(size_t)blockIdx.x * 2048 + qloc * 32 + nt * 16 + m] = f2bf(Oacc[nt][r]);
    if (m == 0) Lpart[(size_t)blockIdx.x * 64 + qloc] = ssum;
  }
}

// ---------------- coarse decoder head + 16->32 align-corners bilinear
__global__ __launch_bounds__(1024) void k_coarse_dec(const float* __restrict__ tokens,
    const float* __restrict__ dWc, const float* __restrict__ dbc,
    float* __restrict__ c_up) {
  int b = blockIdx.x;
  int t = threadIdx.x;
  __shared__ float c[NCc];
  if (t < NCc) {
    const float* row = tokens + (size_t)(b * NTOK + t) * DD;
    float a = 0.f;
    for (int d = 0; d < DD; ++d) a += row[d] * dWc[d];
    c[t] = a + dbc[0];
  }
  __syncthreads();
  int oy = t >> 5, ox = t & 31;
  float ys = oy * (15.f / 31.f);
  float xs = ox * (15.f / 31.f);
  int y0 = (int)floorf(ys); int y1 = min(y0 + 1, 15); float wy = ys - (float)y0;
  int x0 = (int)floorf(xs); int x1 = min(x0 + 1, 15); float wx = xs - (float)x0;
  float v = c[y0 * 16 + x0] * (1.f - wy) * (1.f - wx)
          + c[y0 * 16 + x1] * (1.f - wy) * wx
          + c[y1 * 16 + x0] * wy * (1.f - wx)
          + c[y1 * 16 + x1] * wy * wx;
  c_up[b * 1024 + t] = v;
}

// ---------------- fine decoder head, mask, scatter back to pixel order
__global__ __launch_bounds__(256) void k_fine_dec(const float* __restrict__ tokens,
    const float* __restrict__ dWf, const float* __restrict__ dbf,
    const float* __restrict__ msort, const int* __restrict__ order,
    float* __restrict__ f_map) {
  int idx = blockIdx.x * 256 + threadIdx.x;  // b*NF + j
  int b = idx >> 10, j = idx & 1023;
  const float* row = tokens + (size_t)(b * NTOK + NCc + j) * DD;
  float a = 0.f;
  for (int d = 0; d < DD; ++d) a += row[d] * dWf[d];
  a = (a + dbf[0]) * msort[b * NFf + j];
  f_map[b * NFf + order[b * NFf + j]] = a;  // 32->32 AC-bilinear is identity
}

// ---------------- fused 2-ch conv3x3 + relu + conv3x3 -> out
__global__ __launch_bounds__(1024) void k_fuse_conv(const float* __restrict__ c_up,
    const float* __restrict__ f_map, const float* __restrict__ fW1,
    const float* __restrict__ fb1, const float* __restrict__ fW2,
    const float* __restrict__ fb2, float* __restrict__ outp) {
  int b = blockIdx.x;
  int t = threadIdx.x;
  int y = t >> 5, x = t & 31;
  __shared__ float fin[2][1024];
  __shared__ float hb[2][1024];
  fin[0][t] = c_up[b * 1024 + t];
  fin[1][t] = f_map[b * 1024 + t];
  __syncthreads();
  for (int oc = 0; oc < 2; ++oc) {
    float a = fb1[oc];
    #pragma unroll
    for (int ic = 0; ic < 2; ++ic)
      #pragma unroll
      for (int ky = 0; ky < 3; ++ky)
        #pragma unroll
        for (int kx = 0; kx < 3; ++kx) {
          int yy = y + ky - 1, xx = x + kx - 1;
          float v = (yy >= 0 && yy < 32 && xx >= 0 && xx < 32)
                        ? fin[ic][yy * 32 + xx] : 0.f;
          a += v * fW1[((oc * 2 + ic) * 3 + ky) * 3 + kx];
        }
    hb[oc][t] = fmaxf(a, 0.f);
  }
  __syncthreads();
  float a = fb2[0];
  #pragma unroll
  for (int ic = 0; ic < 2; ++ic)
    #pragma unroll
    for (int ky = 0; ky < 3; ++ky)
      #pragma unroll
      for (int kx = 0; kx < 3; ++kx) {
        int yy = y + ky - 1, xx = x + kx - 1;
        float v = (yy >= 0 && yy < 32 && xx >= 0 && xx < 32)
                      ? hb[ic][yy * 32 + xx] : 0.f;
        a += v * fW2[(ic * 3 + ky) * 3 + kx];
      }
  outp[b * 1024 + t] = a;
}

extern "C" void kernel_launch(void* const* d_in, const int* in_sizes, int n_in,
                              void* d_out, int out_size, void* d_ws, size_t ws_size,
                              hipStream_t stream) {
  const float* x    = (const float*)d_in[0];
  const float* Wpc  = (const float*)d_in[1];
  const float* bpc  = (const float*)d_in[2];
  const float* Wpf  = (const float*)d_in[3];
  const float* bpf  = (const float*)d_in[4];
  const float* te   = (const float*)d_in[5];
  const float* ln1g = (const float*)d_in[6];
  const float* ln1b = (const float*)d_in[7];
  const float* Wqkv = (const float*)d_in[8];
  const float* Wo   = (const float*)d_in[9];
  const float* bo   = (const float*)d_in[10];
  const float* ln2g = (const float*)d_in[11];
  const float* ln2b = (const float*)d_in[12];
  const float* W1   = (const float*)d_in[13];
  const float* b1   = (const float*)d_in[14];
  const float* W2   = (const float*)d_in[15];
  const float* b2   = (const float*)d_in[16];
  const float* dWc  = (const float*)d_in[17];
  const float* dbc  = (const float*)d_in[18];
  const float* dWf  = (const float*)d_in[19];
  const float* dbf  = (const float*)d_in[20];
  const float* fW1  = (const float*)d_in[21];
  const float* fb1  = (const float*)d_in[22];
  const float* fW2  = (const float*)d_in[23];
  const float* fb2  = (const float*)d_in[24];

  char* ws = (char*)d_ws;
  float* tokens = (float*)ws;                 ws += 1310720 * 4;   // fp32 [B*N,128]
  short* ybuf   = (short*)ws;                 ws += 1310720 * 2;   // bf16
  short* qkvb   = (short*)ws;                 ws += 3932160 * 2;   // bf16 [B*N,384]
  short* hbuf   = (short*)ws;                 ws += 2621440 * 2;   // bf16 [B*N,256]
  short* Opart  = (short*)ws;                 ws += (size_t)(Bx * HEADS * NQT * SPLIT) * 2048 * 2;
  float* Lpart  = (float*)ws;                 ws += (size_t)(Bx * HEADS * NQT * SPLIT) * 64 * 4;
  short* WtQKV  = (short*)ws;                 ws += 98304 * 2;     // [L][384][128]
  short* WtO    = (short*)ws;                 ws += 32768 * 2;     // [L][128][128]
  short* Wt1    = (short*)ws;                 ws += 65536 * 2;     // [L][256][128]
  short* Wt2    = (short*)ws;                 ws += 65536 * 2;     // [L][128][256]
  float* ebuf   = (float*)ws;                 ws += 8192 * 4;
  float* msort  = (float*)ws;                 ws += 8192 * 4;
  float* c_up   = (float*)ws;                 ws += 8192 * 4;
  float* f_map  = (float*)ws;                 ws += 8192 * 4;
  int*   order  = (int*)ws;                   ws += 8192 * 4;
  int*   inv    = (int*)ws;                   ws += 8192 * 4;

  const int M = Bx * NTOK;                    // 10240

  k_prep_w<<<1024, 256, 0, stream>>>(Wqkv, Wo, W1, W2, WtQKV, WtO, Wt1, Wt2);
  k_sobel<<<Bx * 64, 256, 0, stream>>>(x, ebuf);
  k_coarse<<<Bx * NCc, 128, 0, stream>>>(x, Wpc, bpc, te, tokens);
  k_edge_sort<<<Bx, 1024, 0, stream>>>(ebuf, order, inv, msort);
  k_fine<<<Bx * NFf, 128, 0, stream>>>(x, Wpf, bpf, te, inv, msort, tokens);

  for (int l = 0; l < LL; ++l) {
    k_ln_bf16<<<M / 4, 256, 0, stream>>>(tokens, ln1g + l * DD, ln1b + l * DD, ybuf);
    k_gemm_mfma<<<dim3(M / 64, 384 / 64), 256, 0, stream>>>(
        ybuf, WtQKV + (size_t)l * 49152, nullptr, nullptr, qkvb, 128, 384, 0);
    k_attn4<<<Bx * HEADS * NQT * SPLIT, 256, 0, stream>>>(qkvb, Opart, Lpart);
    k_gemm_wo<<<dim3(M / 64, 2), 256, 0, stream>>>(
        Opart, Lpart, WtO + (size_t)l * 16384, bo + l * DD, tokens);
    k_ln_bf16<<<M / 4, 256, 0, stream>>>(tokens, ln2g + l * DD, ln2b + l * DD, ybuf);
    k_gemm_mfma<<<dim3(M / 64, 256 / 64), 256, 0, stream>>>(
        ybuf, Wt1 + (size_t)l * 32768, b1 + l * 256, nullptr, hbuf, 128, 256, 1);
    k_gemm_mfma<<<dim3(M / 64, 128 / 64), 256, 0, stream>>>(
        hbuf, Wt2 + (size_t)l * 32768, b2 + l * DD, tokens, nullptr, 256, 128, 0);
  }

  k_coarse_dec<<<Bx, 1024, 0, stream>>>(tokens, dWc, dbc, c_up);
  k_fine_dec<<<Bx * NFf / 256, 256, 0, stream>>>(tokens, dWf, dbf, msort, order, f_map);
  k_fuse_conv<<<Bx, 1024, 0, stream>>>(c_up, f_map, fW1, fb1, fW2, fb2, (float*)d_out);
}